// Round 3
// baseline (560.261 us; speedup 1.0000x reference)
//
#include <hip/hip_runtime.h>

#define NEG_SLOPE 0.2f

// ---------------- init: hist=1 (self-loop), zero alpha-dot accumulators ----------------

__global__ void k_init(int* hist, float* as1, float* ad1, int N) {
    int i = blockIdx.x * 256 + threadIdx.x;
    if (i < N) {
        hist[i] = 1;
        *(float4*)(as1 + (size_t)i * 4) = make_float4(0.f, 0.f, 0.f, 0.f);
        *(float4*)(ad1 + (size_t)i * 4) = make_float4(0.f, 0.f, 0.f, 0.f);
    }
}

__global__ void k_count(const int* __restrict__ dst, int* hist, int E) {
    int i = blockIdx.x * 256 + threadIdx.x;
    if (i < E) atomicAdd(&hist[dst[i]], 1);
}

// single-block scan (shuffle-based, 3 barriers/chunk), fused cursor/col self-loop init
__global__ void k_scan(const int* __restrict__ hist, int* __restrict__ rowptr,
                       int* __restrict__ cursor, int* __restrict__ col, int n) {
    __shared__ int wsums[16];
    const int tid = threadIdx.x;
    const int lane = tid & 63;
    const int wave = tid >> 6;
    int carry = 0;  // live only in thread 0
    const int CHUNK = 1024 * 8;
    for (int base = 0; base < n; base += CHUNK) {
        int idx0 = base + tid * 8;
        int v[8];
        int tsum = 0;
#pragma unroll
        for (int i = 0; i < 8; ++i) {
            int idx = idx0 + i;
            v[i] = (idx < n) ? hist[idx] : 0;
            tsum += v[i];
        }
        // wave-inclusive scan of tsum
        int incl = tsum;
#pragma unroll
        for (int off = 1; off < 64; off <<= 1) {
            int t = __shfl_up(incl, off);
            if (lane >= off) incl += t;
        }
        if (lane == 63) wsums[wave] = incl;
        __syncthreads();
        if (tid == 0) {
            int s = carry;
#pragma unroll
            for (int w = 0; w < 16; ++w) {
                int t = wsums[w];
                wsums[w] = s;
                s += t;
            }
            carry = s;
        }
        __syncthreads();
        int excl = wsums[wave] + incl - tsum;
#pragma unroll
        for (int i = 0; i < 8; ++i) {
            int idx = idx0 + i;
            if (idx < n) {
                rowptr[idx] = excl;
                col[excl] = idx;        // self-loop in slot 0 of each segment
                cursor[idx] = excl + 1;
            }
            excl += v[i];
        }
        __syncthreads();  // protect wsums for next chunk
    }
    if (tid == 0) rowptr[n] = carry;
}

__global__ void k_scatter(const int* __restrict__ src, const int* __restrict__ dst,
                          int* cursor, int* col, int E) {
    int i = blockIdx.x * 256 + threadIdx.x;
    if (i < E) {
        int p = atomicAdd(&cursor[dst[i]], 1);
        col[p] = src[i];
    }
}

// ---------------- GEMM1: h1[N,256] = x[N,256] @ W1[256,256], fused alpha1 dots ----------------
// 128x128 tile, 8x8 per thread, float4 LDS fragments (A staged k-major).
// Epilogue: per-row per-head partial dots with a_src/a_dst, shuffle-reduced, atomicAdd.

__global__ __launch_bounds__(256, 4) void k_gemm1(const float* __restrict__ x,
                                                  const float* __restrict__ W,
                                                  const float* __restrict__ a_src,
                                                  const float* __restrict__ a_dst,
                                                  float* __restrict__ h1,
                                                  float* __restrict__ as1,
                                                  float* __restrict__ ad1, int N) {
    __shared__ float As[16 * 132];  // k-major: As[k][m], stride 132
    __shared__ float Bs[16 * 132];  // k-major: Bs[k][n], stride 132
    const int tid = threadIdx.x;
    const int tx8 = tid & 15;   // col group
    const int ty8 = tid >> 4;   // row group
    const int row0 = blockIdx.y * 128;
    const int col0 = blockIdx.x * 128;
    float acc[8][8] = {};
    for (int k0 = 0; k0 < 256; k0 += 16) {
        // stage A with transpose: 128 rows x 16 k
#pragma unroll
        for (int i = 0; i < 2; ++i) {
            int idx = tid + 256 * i;       // 0..511
            int r = idx >> 2;              // 0..127
            int kc = (idx & 3) * 4;        // 0,4,8,12
            int row = row0 + r;
            float4 v = (row < N) ? *(const float4*)(x + (size_t)row * 256 + k0 + kc)
                                 : make_float4(0.f, 0.f, 0.f, 0.f);
            As[(kc + 0) * 132 + r] = v.x;
            As[(kc + 1) * 132 + r] = v.y;
            As[(kc + 2) * 132 + r] = v.z;
            As[(kc + 3) * 132 + r] = v.w;
        }
        // stage B: 16 k x 128 cols (already k-major in W)
#pragma unroll
        for (int i = 0; i < 2; ++i) {
            int idx = tid + 256 * i;
            int k = idx >> 5;              // 0..15
            int cc = (idx & 31) * 4;       // 0..124
            *(float4*)(Bs + k * 132 + cc) =
                *(const float4*)(W + (size_t)(k0 + k) * 256 + col0 + cc);
        }
        __syncthreads();
#pragma unroll
        for (int kk = 0; kk < 16; ++kk) {
            float4 a0 = *(const float4*)(As + kk * 132 + ty8 * 8);
            float4 a1 = *(const float4*)(As + kk * 132 + ty8 * 8 + 4);
            float4 b0 = *(const float4*)(Bs + kk * 132 + tx8 * 8);
            float4 b1 = *(const float4*)(Bs + kk * 132 + tx8 * 8 + 4);
            float a[8] = {a0.x, a0.y, a0.z, a0.w, a1.x, a1.y, a1.z, a1.w};
            float b[8] = {b0.x, b0.y, b0.z, b0.w, b1.x, b1.y, b1.z, b1.w};
#pragma unroll
            for (int ii = 0; ii < 8; ++ii)
#pragma unroll
                for (int jj = 0; jj < 8; ++jj)
                    acc[ii][jj] = fmaf(a[ii], b[jj], acc[ii][jj]);
        }
        __syncthreads();
    }
    // preload attention vectors for this thread's 8 columns (one head per lane)
    float av[8], dv[8];
#pragma unroll
    for (int jj = 0; jj < 8; ++jj) {
        av[jj] = a_src[col0 + tx8 * 8 + jj];
        dv[jj] = a_dst[col0 + tx8 * 8 + jj];
    }
    const int headbase = col0 >> 6;            // 2 heads per 128-col block
    const int headoff = tx8 >> 3;              // 0 or 1
#pragma unroll
    for (int ii = 0; ii < 8; ++ii) {
        int row = row0 + ty8 * 8 + ii;
        if (row < N) {
            float4 s0 = make_float4(acc[ii][0], acc[ii][1], acc[ii][2], acc[ii][3]);
            float4 s1 = make_float4(acc[ii][4], acc[ii][5], acc[ii][6], acc[ii][7]);
            *(float4*)(h1 + (size_t)row * 256 + col0 + tx8 * 8) = s0;
            *(float4*)(h1 + (size_t)row * 256 + col0 + tx8 * 8 + 4) = s1;
        }
        // partial head dots over this thread's 8 cols
        float va = 0.f, vd = 0.f;
#pragma unroll
        for (int jj = 0; jj < 8; ++jj) {
            va = fmaf(acc[ii][jj], av[jj], va);
            vd = fmaf(acc[ii][jj], dv[jj], vd);
        }
        // reduce over the 8 lanes sharing (row, head)
#pragma unroll
        for (int mq = 1; mq < 8; mq <<= 1) {
            va += __shfl_xor(va, mq);
            vd += __shfl_xor(vd, mq);
        }
        if ((tx8 & 7) == 0 && row < N) {
            atomicAdd(&as1[(size_t)row * 4 + headbase + headoff], va);
            atomicAdd(&ad1[(size_t)row * 4 + headbase + headoff], vd);
        }
    }
}

// ---------------- edge1: unnormalized softmax weights (all 4 heads) ----------------

__global__ void k_edge1(const float* __restrict__ as1, const float* __restrict__ ad1,
                        const int* __restrict__ rowptr, const int* __restrict__ col,
                        float* __restrict__ alpha, float* __restrict__ inv1, int N) {
    int n = blockIdx.x * 4 + (threadIdx.x >> 6);
    if (n >= N) return;
    int l = threadIdx.x & 63;
    int beg = __builtin_amdgcn_readfirstlane(rowptr[n]);
    int end = __builtin_amdgcn_readfirstlane(rowptr[n + 1]);
    float4 ad = *(const float4*)(ad1 + (size_t)n * 4);
    float4 sum = make_float4(0.f, 0.f, 0.f, 0.f);
    for (int j = beg + l; j < end; j += 64) {
        int src = col[j];
        float4 as = *(const float4*)(as1 + (size_t)src * 4);
        float4 e;
        e.x = as.x + ad.x; e.x = fmaxf(e.x, NEG_SLOPE * e.x);
        e.y = as.y + ad.y; e.y = fmaxf(e.y, NEG_SLOPE * e.y);
        e.z = as.z + ad.z; e.z = fmaxf(e.z, NEG_SLOPE * e.z);
        e.w = as.w + ad.w; e.w = fmaxf(e.w, NEG_SLOPE * e.w);
        float4 p;
        p.x = __expf(e.x); p.y = __expf(e.y); p.z = __expf(e.z); p.w = __expf(e.w);
        *(float4*)(alpha + (size_t)j * 4) = p;
        sum.x += p.x; sum.y += p.y; sum.z += p.z; sum.w += p.w;
    }
#pragma unroll
    for (int mq = 1; mq < 64; mq <<= 1) {
        sum.x += __shfl_xor(sum.x, mq);
        sum.y += __shfl_xor(sum.y, mq);
        sum.z += __shfl_xor(sum.z, mq);
        sum.w += __shfl_xor(sum.w, mq);
    }
    if (l == 0) {
        float4 iv;
        iv.x = 1.f / (sum.x + 1e-16f);
        iv.y = 1.f / (sum.y + 1e-16f);
        iv.z = 1.f / (sum.z + 1e-16f);
        iv.w = 1.f / (sum.w + 1e-16f);
        *(float4*)(inv1 + (size_t)n * 4) = iv;
    }
}

// ---------------- gather1: acc = sum_j p_j * h1[src_j], then *inv + bias + ELU ----------------
// One wave per dst node; lane covers 4 channels. Unroll 4: four independent row-gathers
// in flight per wave. Edge metadata wave-uniform -> scalar loads.

__global__ __launch_bounds__(256) void k_gather1(
        const float* __restrict__ h1, const float* __restrict__ alpha,
        const float* __restrict__ inv1, const int* __restrict__ rowptr,
        const int* __restrict__ col, const float* __restrict__ b1,
        float* __restrict__ h2in, int N) {
    int n = blockIdx.x * 4 + (threadIdx.x >> 6);
    if (n >= N) return;
    int l = threadIdx.x & 63;
    int head = l >> 4;
    int beg = __builtin_amdgcn_readfirstlane(rowptr[n]);
    int end = __builtin_amdgcn_readfirstlane(rowptr[n + 1]);
    float4 a0 = make_float4(0.f, 0.f, 0.f, 0.f);
    float4 a1 = make_float4(0.f, 0.f, 0.f, 0.f);
    float4 a2 = make_float4(0.f, 0.f, 0.f, 0.f);
    float4 a3 = make_float4(0.f, 0.f, 0.f, 0.f);
    int j = beg;
    for (; j + 3 < end; j += 4) {
        int s0 = __builtin_amdgcn_readfirstlane(col[j]);
        int s1 = __builtin_amdgcn_readfirstlane(col[j + 1]);
        int s2 = __builtin_amdgcn_readfirstlane(col[j + 2]);
        int s3 = __builtin_amdgcn_readfirstlane(col[j + 3]);
        float p0 = alpha[(size_t)(j + 0) * 4 + head];
        float p1 = alpha[(size_t)(j + 1) * 4 + head];
        float p2 = alpha[(size_t)(j + 2) * 4 + head];
        float p3 = alpha[(size_t)(j + 3) * 4 + head];
        float4 h0 = *(const float4*)(h1 + (size_t)s0 * 256 + l * 4);
        float4 h1v = *(const float4*)(h1 + (size_t)s1 * 256 + l * 4);
        float4 h2 = *(const float4*)(h1 + (size_t)s2 * 256 + l * 4);
        float4 h3 = *(const float4*)(h1 + (size_t)s3 * 256 + l * 4);
        a0.x = fmaf(p0, h0.x, a0.x); a0.y = fmaf(p0, h0.y, a0.y);
        a0.z = fmaf(p0, h0.z, a0.z); a0.w = fmaf(p0, h0.w, a0.w);
        a1.x = fmaf(p1, h1v.x, a1.x); a1.y = fmaf(p1, h1v.y, a1.y);
        a1.z = fmaf(p1, h1v.z, a1.z); a1.w = fmaf(p1, h1v.w, a1.w);
        a2.x = fmaf(p2, h2.x, a2.x); a2.y = fmaf(p2, h2.y, a2.y);
        a2.z = fmaf(p2, h2.z, a2.z); a2.w = fmaf(p2, h2.w, a2.w);
        a3.x = fmaf(p3, h3.x, a3.x); a3.y = fmaf(p3, h3.y, a3.y);
        a3.z = fmaf(p3, h3.z, a3.z); a3.w = fmaf(p3, h3.w, a3.w);
    }
    for (; j < end; ++j) {
        int s0 = __builtin_amdgcn_readfirstlane(col[j]);
        float p0 = alpha[(size_t)j * 4 + head];
        float4 h0 = *(const float4*)(h1 + (size_t)s0 * 256 + l * 4);
        a0.x = fmaf(p0, h0.x, a0.x); a0.y = fmaf(p0, h0.y, a0.y);
        a0.z = fmaf(p0, h0.z, a0.z); a0.w = fmaf(p0, h0.w, a0.w);
    }
    a0.x += a1.x + a2.x + a3.x;
    a0.y += a1.y + a2.y + a3.y;
    a0.z += a1.z + a2.z + a3.z;
    a0.w += a1.w + a2.w + a3.w;
    float iv = inv1[(size_t)n * 4 + head];
    float4 bb = *(const float4*)(b1 + l * 4);
    float4 v;
    v.x = a0.x * iv + bb.x;
    v.y = a0.y * iv + bb.y;
    v.z = a0.z * iv + bb.z;
    v.w = a0.w * iv + bb.w;
    v.x = (v.x > 0.f) ? v.x : (__expf(v.x) - 1.f);
    v.y = (v.y > 0.f) ? v.y : (__expf(v.y) - 1.f);
    v.z = (v.z > 0.f) ? v.z : (__expf(v.z) - 1.f);
    v.w = (v.w > 0.f) ? v.w : (__expf(v.w) - 1.f);
    *(float4*)(h2in + (size_t)n * 256 + l * 4) = v;
}

// ---------------- GEMM2: z[N,32] = h2in[N,256] @ W2[256,32], fused alpha2 dots ----------------

__global__ __launch_bounds__(256) void k_gemm2(const float* __restrict__ h,
                                               const float* __restrict__ W2,
                                               const float* __restrict__ asrc,
                                               const float* __restrict__ adst,
                                               float* __restrict__ z, float* __restrict__ as2,
                                               float* __restrict__ ad2, int N) {
    __shared__ float Ws[256 * 32];      // full W2, k-major (row-major already)
    __shared__ float Hs[32 * 68];       // 32 rows x 64 k chunk, stride 68
    const int tid = threadIdx.x;
    const int r = tid >> 3;             // 0..31 row in block
    const int cg = tid & 7;             // col group (4 cols)
    const int row0 = blockIdx.x * 32;
    const int row = row0 + r;
    for (int i = tid; i < 256 * 32; i += 256) Ws[i] = W2[i];
    float4 acc = make_float4(0.f, 0.f, 0.f, 0.f);
    for (int k0 = 0; k0 < 256; k0 += 64) {
        __syncthreads();
#pragma unroll
        for (int i = 0; i < 2; ++i) {
            int idx = tid + 256 * i;     // 0..511
            int rr = idx >> 4;           // 0..31
            int c4 = (idx & 15) * 4;     // 0..60
            int rw = row0 + rr;
            float4 v = (rw < N) ? *(const float4*)(h + (size_t)rw * 256 + k0 + c4)
                                : make_float4(0.f, 0.f, 0.f, 0.f);
            *(float4*)(Hs + rr * 68 + c4) = v;
        }
        __syncthreads();
#pragma unroll
        for (int k = 0; k < 64; k += 4) {
            float4 hv = *(const float4*)(Hs + r * 68 + k);
            float4 w0 = *(const float4*)(Ws + (k0 + k) * 32 + cg * 4);
            float4 w1 = *(const float4*)(Ws + (k0 + k + 1) * 32 + cg * 4);
            float4 w2 = *(const float4*)(Ws + (k0 + k + 2) * 32 + cg * 4);
            float4 w3 = *(const float4*)(Ws + (k0 + k + 3) * 32 + cg * 4);
            acc.x = fmaf(hv.x, w0.x, acc.x); acc.y = fmaf(hv.x, w0.y, acc.y);
            acc.z = fmaf(hv.x, w0.z, acc.z); acc.w = fmaf(hv.x, w0.w, acc.w);
            acc.x = fmaf(hv.y, w1.x, acc.x); acc.y = fmaf(hv.y, w1.y, acc.y);
            acc.z = fmaf(hv.y, w1.z, acc.z); acc.w = fmaf(hv.y, w1.w, acc.w);
            acc.x = fmaf(hv.z, w2.x, acc.x); acc.y = fmaf(hv.z, w2.y, acc.y);
            acc.z = fmaf(hv.z, w2.z, acc.z); acc.w = fmaf(hv.z, w2.w, acc.w);
            acc.x = fmaf(hv.w, w3.x, acc.x); acc.y = fmaf(hv.w, w3.y, acc.y);
            acc.z = fmaf(hv.w, w3.z, acc.z); acc.w = fmaf(hv.w, w3.w, acc.w);
        }
    }
    float4 a4 = *(const float4*)(asrc + cg * 4);
    float4 d4 = *(const float4*)(adst + cg * 4);
    float va = acc.x * a4.x + acc.y * a4.y + acc.z * a4.z + acc.w * a4.w;
    float vd = acc.x * d4.x + acc.y * d4.y + acc.z * d4.z + acc.w * d4.w;
#pragma unroll
    for (int mq = 1; mq < 8; mq <<= 1) {
        va += __shfl_xor(va, mq);
        vd += __shfl_xor(vd, mq);
    }
    if (row < N) {
        *(float4*)(z + (size_t)row * 32 + cg * 4) = acc;
        if (cg == 0) {
            as2[row] = va;
            ad2[row] = vd;
        }
    }
}

// ---------------- edge2: unnormalized softmax weights, 1 head ----------------

__global__ void k_edge2(const float* __restrict__ as2, const float* __restrict__ ad2,
                        const int* __restrict__ rowptr, const int* __restrict__ col,
                        float* __restrict__ alpha2, float* __restrict__ inv2, int N) {
    int n = blockIdx.x * 4 + (threadIdx.x >> 6);
    if (n >= N) return;
    int l = threadIdx.x & 63;
    int beg = __builtin_amdgcn_readfirstlane(rowptr[n]);
    int end = __builtin_amdgcn_readfirstlane(rowptr[n + 1]);
    float adn = ad2[n];
    float sum = 0.f;
    for (int j = beg + l; j < end; j += 64) {
        int src = col[j];
        float e = as2[src] + adn;
        e = fmaxf(e, NEG_SLOPE * e);
        float p = __expf(e);
        alpha2[j] = p;
        sum += p;
    }
#pragma unroll
    for (int mq = 1; mq < 64; mq <<= 1) sum += __shfl_xor(sum, mq);
    if (l == 0) inv2[n] = 1.f / (sum + 1e-16f);
}

// ---------------- gather2: out = (sum_j p_j * z[src_j]) * inv + b2 ----------------

__global__ void k_gather2(const float* __restrict__ z, const float* __restrict__ alpha2,
                          const float* __restrict__ inv2, const int* __restrict__ rowptr,
                          const int* __restrict__ col, const float* __restrict__ b2,
                          float* __restrict__ out, int N) {
    int n = blockIdx.x * 4 + (threadIdx.x >> 6);
    if (n >= N) return;
    int l = threadIdx.x & 63;
    int eo = l >> 3;                    // edge offset 0..7
    int cg = l & 7;                     // 4-channel group
    int beg = __builtin_amdgcn_readfirstlane(rowptr[n]);
    int end = __builtin_amdgcn_readfirstlane(rowptr[n + 1]);
    float4 acc = make_float4(0.f, 0.f, 0.f, 0.f);
    for (int j0 = beg; j0 < end; j0 += 8) {
        int idx = j0 + eo;
        bool valid = idx < end;
        int idc = valid ? idx : (end - 1);
        int src = col[idc];
        float p = valid ? alpha2[idc] : 0.f;
        float4 zv = *(const float4*)(z + (size_t)src * 32 + cg * 4);
        acc.x = fmaf(p, zv.x, acc.x); acc.y = fmaf(p, zv.y, acc.y);
        acc.z = fmaf(p, zv.z, acc.z); acc.w = fmaf(p, zv.w, acc.w);
    }
#pragma unroll
    for (int mq = 8; mq < 64; mq <<= 1) {
        acc.x += __shfl_xor(acc.x, mq);
        acc.y += __shfl_xor(acc.y, mq);
        acc.z += __shfl_xor(acc.z, mq);
        acc.w += __shfl_xor(acc.w, mq);
    }
    if (eo == 0) {
        float iv = inv2[n];
        float4 bb = *(const float4*)(b2 + cg * 4);
        float4 v;
        v.x = acc.x * iv + bb.x;
        v.y = acc.y * iv + bb.y;
        v.z = acc.z * iv + bb.z;
        v.w = acc.w * iv + bb.w;
        *(float4*)(out + (size_t)n * 32 + cg * 4) = v;
    }
}

// ---------------- launch ----------------

extern "C" void kernel_launch(void* const* d_in, const int* in_sizes, int n_in,
                              void* d_out, int out_size, void* d_ws, size_t ws_size,
                              hipStream_t stream) {
    const float* x    = (const float*)d_in[0];
    const int*   ei   = (const int*)d_in[1];
    const float* W1   = (const float*)d_in[2];
    const float* a_s1 = (const float*)d_in[3];
    const float* a_d1 = (const float*)d_in[4];
    const float* b1   = (const float*)d_in[5];
    const float* W2   = (const float*)d_in[6];
    const float* a_s2 = (const float*)d_in[7];
    const float* a_d2 = (const float*)d_in[8];
    const float* b2   = (const float*)d_in[9];
    float* out = (float*)d_out;

    const int N = in_sizes[0] / 256;
    const int E = in_sizes[1] / 2;
    const int EP = E + N;  // with self-loops
    const int* srcIdx = ei;
    const int* dstIdx = ei + E;

    char* ws = (char*)d_ws;
    size_t off = 0;
    auto alloc = [&](size_t bytes) {
        void* p = ws + off;
        off += (bytes + 255) & ~(size_t)255;
        return p;
    };
    float* h1     = (float*)alloc((size_t)N * 256 * 4);   // reused as z after gather1
    float* h2in   = (float*)alloc((size_t)N * 256 * 4);
    float* alpha  = (float*)alloc((size_t)EP * 16);       // layer1 float4/edge; reused as alpha2
    float* as1    = (float*)alloc((size_t)N * 16);        // reused as as2
    float* ad1    = (float*)alloc((size_t)N * 16);        // reused as ad2
    float* inv1   = (float*)alloc((size_t)N * 16);        // reused as inv2
    int*   hist   = (int*)alloc((size_t)N * 4);
    int*   cursor = (int*)alloc((size_t)N * 4);
    int*   rowptr = (int*)alloc((size_t)(N + 1) * 4);
    int*   col    = (int*)alloc((size_t)EP * 4);

    float* z      = h1;
    float* alpha2 = alpha;
    float* as2    = as1;
    float* ad2    = ad1;
    float* inv2   = inv1;

    // CSR build (dst-sorted adjacency, self-loops included) + accumulator init
    k_init<<<(N + 255) / 256, 256, 0, stream>>>(hist, as1, ad1, N);
    k_count<<<(E + 255) / 256, 256, 0, stream>>>(dstIdx, hist, E);
    k_scan<<<1, 1024, 0, stream>>>(hist, rowptr, cursor, col, N);
    k_scatter<<<(E + 255) / 256, 256, 0, stream>>>(srcIdx, dstIdx, cursor, col, E);

    // layer 1
    dim3 g1(2, (N + 127) / 128);
    k_gemm1<<<g1, 256, 0, stream>>>(x, W1, a_s1, a_d1, h1, as1, ad1, N);
    k_edge1<<<(N + 3) / 4, 256, 0, stream>>>(as1, ad1, rowptr, col, alpha, inv1, N);
    k_gather1<<<(N + 3) / 4, 256, 0, stream>>>(h1, alpha, inv1, rowptr, col, b1, h2in, N);

    // layer 2
    k_gemm2<<<(N + 31) / 32, 256, 0, stream>>>(h2in, W2, a_s2, a_d2, z, as2, ad2, N);
    k_edge2<<<(N + 3) / 4, 256, 0, stream>>>(as2, ad2, rowptr, col, alpha2, inv2, N);
    k_gather2<<<(N + 3) / 4, 256, 0, stream>>>(z, alpha2, inv2, rowptr, col, b2, out, N);
}

// Round 4
// 450.972 us; speedup vs baseline: 1.2423x; 1.2423x over previous
//
#include <hip/hip_runtime.h>

#define NEG_SLOPE 0.2f

typedef short bf16x8 __attribute__((ext_vector_type(8)));
typedef float f32x4 __attribute__((ext_vector_type(4)));
typedef _Float16 half4v __attribute__((ext_vector_type(4)));

// split fp32 into hi (truncated bf16) + lo (RNE bf16 of remainder): x ~= hi + lo, err ~2^-17*x
__device__ inline void split_bf16(float x, short& hi, short& lo) {
    unsigned xb = __float_as_uint(x);
    hi = (short)(xb >> 16);
    float hif = __uint_as_float(xb & 0xFFFF0000u);
    float rem = x - hif;
    unsigned rb = __float_as_uint(rem);
    unsigned r = rb + 0x7FFFu + ((rb >> 16) & 1u);
    lo = (short)(r >> 16);
}

// ---------------- CSR build ----------------

__global__ void k_init(int* hist, int N) {
    int i = blockIdx.x * 256 + threadIdx.x;
    if (i < N) hist[i] = 1;  // self-loop pre-counted
}

__global__ void k_count(const int* __restrict__ dst, int* hist, int E) {
    int i = blockIdx.x * 256 + threadIdx.x;
    if (i < E) atomicAdd(&hist[dst[i]], 1);
}

// single-block scan (shuffle-based), fused cursor/col self-loop init
__global__ void k_scan(const int* __restrict__ hist, int* __restrict__ rowptr,
                       int* __restrict__ cursor, int* __restrict__ col, int n) {
    __shared__ int wsums[16];
    const int tid = threadIdx.x;
    const int lane = tid & 63;
    const int wave = tid >> 6;
    int carry = 0;  // live only in thread 0
    const int CHUNK = 1024 * 8;
    for (int base = 0; base < n; base += CHUNK) {
        int idx0 = base + tid * 8;
        int v[8];
        int tsum = 0;
#pragma unroll
        for (int i = 0; i < 8; ++i) {
            int idx = idx0 + i;
            v[i] = (idx < n) ? hist[idx] : 0;
            tsum += v[i];
        }
        int incl = tsum;
#pragma unroll
        for (int off = 1; off < 64; off <<= 1) {
            int t = __shfl_up(incl, off);
            if (lane >= off) incl += t;
        }
        if (lane == 63) wsums[wave] = incl;
        __syncthreads();
        if (tid == 0) {
            int s = carry;
#pragma unroll
            for (int w = 0; w < 16; ++w) {
                int t = wsums[w];
                wsums[w] = s;
                s += t;
            }
            carry = s;
        }
        __syncthreads();
        int excl = wsums[wave] + incl - tsum;
#pragma unroll
        for (int i = 0; i < 8; ++i) {
            int idx = idx0 + i;
            if (idx < n) {
                rowptr[idx] = excl;
                col[excl] = idx;
                cursor[idx] = excl + 1;
            }
            excl += v[i];
        }
        __syncthreads();
    }
    if (tid == 0) rowptr[n] = carry;
}

__global__ void k_scatter(const int* __restrict__ src, const int* __restrict__ dst,
                          int* cursor, int* col, int E) {
    int i = blockIdx.x * 256 + threadIdx.x;
    if (i < E) {
        int p = atomicAdd(&cursor[dst[i]], 1);
        col[p] = src[i];
    }
}

// ---------------- GEMM1 (split-bf16 MFMA): h1[N,256](fp16) = x @ W1, fused alpha1 dots ----------
// 128x128 block tile, 4 waves (2x2), each wave 64x64 = 4x4 MFMA 16x16x32_bf16 tiles.
// C = Ah*Bh + Ah*Bl + Al*Bh in fp32 acc (split-bf16 ~ fp32 accurate).
// Epilogue: h1 stored fp16; per-(row,head) a_src/a_dst dots via 16-lane butterfly, plain store
// (each (row,head) is produced by exactly one wave -> no atomics).

__global__ __launch_bounds__(256) void k_gemm1(
        const float* __restrict__ x, const float* __restrict__ W,
        const float* __restrict__ a_src, const float* __restrict__ a_dst,
        _Float16* __restrict__ h1, float* __restrict__ as1, float* __restrict__ ad1, int N) {
    __shared__ short Ah[128 * 40];  // [m][k], stride 40 (pad: conflict-free b128)
    __shared__ short Al[128 * 40];
    __shared__ short Bh[128 * 40];  // [n][k], stride 40
    __shared__ short Bl[128 * 40];
    const int tid = threadIdx.x;
    const int lane = tid & 63;
    const int wave = tid >> 6;
    const int wr = wave & 1, wc = wave >> 1;
    const int row0 = blockIdx.y * 128;
    const int col0 = blockIdx.x * 128;
    const int m15 = lane & 15, quad = lane >> 4;

    f32x4 acc[4][4] = {};

    const int arow = tid >> 1;             // A-staging: row 0..127
    const int akseg = (tid & 1) * 16;      // k-half 0 or 16
    const int bcol = tid & 127;            // B-staging: col 0..127
    const int bkh = (tid >> 7) * 16;       // k-half 0 or 16

    for (int k0 = 0; k0 < 256; k0 += 32) {
        // stage A: 128 rows x 32 k (coalesced float4), split to hi/lo bf16
        {
            int row = row0 + arow;
            float vals[16];
            if (row < N) {
#pragma unroll
                for (int i = 0; i < 4; ++i) {
                    float4 v = *(const float4*)(x + (size_t)row * 256 + k0 + akseg + i * 4);
                    vals[i * 4 + 0] = v.x; vals[i * 4 + 1] = v.y;
                    vals[i * 4 + 2] = v.z; vals[i * 4 + 3] = v.w;
                }
            } else {
#pragma unroll
                for (int i = 0; i < 16; ++i) vals[i] = 0.f;
            }
            short hbuf[16], lbuf[16];
#pragma unroll
            for (int i = 0; i < 16; ++i) split_bf16(vals[i], hbuf[i], lbuf[i]);
            *(bf16x8*)&Ah[arow * 40 + akseg]     = *(bf16x8*)&hbuf[0];
            *(bf16x8*)&Ah[arow * 40 + akseg + 8] = *(bf16x8*)&hbuf[8];
            *(bf16x8*)&Al[arow * 40 + akseg]     = *(bf16x8*)&lbuf[0];
            *(bf16x8*)&Al[arow * 40 + akseg + 8] = *(bf16x8*)&lbuf[8];
        }
        // stage B with transpose: W[k][col] -> Bs[col][k] (coalesced per-k across lanes)
        {
            float vals[16];
#pragma unroll
            for (int k = 0; k < 16; ++k)
                vals[k] = W[(size_t)(k0 + bkh + k) * 256 + col0 + bcol];
            short hbuf[16], lbuf[16];
#pragma unroll
            for (int i = 0; i < 16; ++i) split_bf16(vals[i], hbuf[i], lbuf[i]);
            *(bf16x8*)&Bh[bcol * 40 + bkh]     = *(bf16x8*)&hbuf[0];
            *(bf16x8*)&Bh[bcol * 40 + bkh + 8] = *(bf16x8*)&hbuf[8];
            *(bf16x8*)&Bl[bcol * 40 + bkh]     = *(bf16x8*)&lbuf[0];
            *(bf16x8*)&Bl[bcol * 40 + bkh + 8] = *(bf16x8*)&lbuf[8];
        }
        __syncthreads();
        // A-frag: m = lane&15, k = quad*8 + j  |  B-frag: n = lane&15, k = quad*8 + j
        bf16x8 ah[4], al[4];
#pragma unroll
        for (int mt = 0; mt < 4; ++mt) {
            int m = wr * 64 + mt * 16 + m15;
            ah[mt] = *(const bf16x8*)&Ah[m * 40 + quad * 8];
            al[mt] = *(const bf16x8*)&Al[m * 40 + quad * 8];
        }
#pragma unroll
        for (int nt = 0; nt < 4; ++nt) {
            int nn = wc * 64 + nt * 16 + m15;
            bf16x8 bh = *(const bf16x8*)&Bh[nn * 40 + quad * 8];
            bf16x8 bl = *(const bf16x8*)&Bl[nn * 40 + quad * 8];
#pragma unroll
            for (int mt = 0; mt < 4; ++mt) {
                acc[mt][nt] = __builtin_amdgcn_mfma_f32_16x16x32_bf16(ah[mt], bh, acc[mt][nt], 0, 0, 0);
                acc[mt][nt] = __builtin_amdgcn_mfma_f32_16x16x32_bf16(ah[mt], bl, acc[mt][nt], 0, 0, 0);
                acc[mt][nt] = __builtin_amdgcn_mfma_f32_16x16x32_bf16(al[mt], bh, acc[mt][nt], 0, 0, 0);
            }
        }
        __syncthreads();
    }
    // epilogue: C/D layout col=lane&15, row=quad*4+reg
    const int head = (col0 >> 6) + wc;     // wave's 64-col range == one head
#pragma unroll
    for (int mt = 0; mt < 4; ++mt) {
        float va[4] = {0.f, 0.f, 0.f, 0.f};
        float vd[4] = {0.f, 0.f, 0.f, 0.f};
#pragma unroll
        for (int nt = 0; nt < 4; ++nt) {
            int colg = col0 + wc * 64 + nt * 16 + m15;
            float asv = a_src[colg];
            float adv = a_dst[colg];
#pragma unroll
            for (int r = 0; r < 4; ++r) {
                float accv = acc[mt][nt][r];
                int row = row0 + wr * 64 + mt * 16 + quad * 4 + r;
                if (row < N) h1[(size_t)row * 256 + colg] = (_Float16)accv;
                va[r] = fmaf(accv, asv, va[r]);
                vd[r] = fmaf(accv, adv, vd[r]);
            }
        }
#pragma unroll
        for (int r = 0; r < 4; ++r) {
#pragma unroll
            for (int mq = 1; mq < 16; mq <<= 1) {  // reduce over the 16 cols (lane&15)
                va[r] += __shfl_xor(va[r], mq);
                vd[r] += __shfl_xor(vd[r], mq);
            }
            int row = row0 + wr * 64 + mt * 16 + quad * 4 + r;
            if (m15 == 0 && row < N) {
                as1[(size_t)row * 4 + head] = va[r];
                ad1[(size_t)row * 4 + head] = vd[r];
            }
        }
    }
}

// ---------------- edge1: unnormalized softmax weights (all 4 heads) ----------------

__global__ void k_edge1(const float* __restrict__ as1, const float* __restrict__ ad1,
                        const int* __restrict__ rowptr, const int* __restrict__ col,
                        float* __restrict__ alpha, float* __restrict__ inv1, int N) {
    int n = blockIdx.x * 4 + (threadIdx.x >> 6);
    if (n >= N) return;
    int l = threadIdx.x & 63;
    int beg = __builtin_amdgcn_readfirstlane(rowptr[n]);
    int end = __builtin_amdgcn_readfirstlane(rowptr[n + 1]);
    float4 ad = *(const float4*)(ad1 + (size_t)n * 4);
    float4 sum = make_float4(0.f, 0.f, 0.f, 0.f);
    for (int j = beg + l; j < end; j += 64) {
        int src = col[j];
        float4 as = *(const float4*)(as1 + (size_t)src * 4);
        float4 e;
        e.x = as.x + ad.x; e.x = fmaxf(e.x, NEG_SLOPE * e.x);
        e.y = as.y + ad.y; e.y = fmaxf(e.y, NEG_SLOPE * e.y);
        e.z = as.z + ad.z; e.z = fmaxf(e.z, NEG_SLOPE * e.z);
        e.w = as.w + ad.w; e.w = fmaxf(e.w, NEG_SLOPE * e.w);
        float4 p;
        p.x = __expf(e.x); p.y = __expf(e.y); p.z = __expf(e.z); p.w = __expf(e.w);
        *(float4*)(alpha + (size_t)j * 4) = p;
        sum.x += p.x; sum.y += p.y; sum.z += p.z; sum.w += p.w;
    }
#pragma unroll
    for (int mq = 1; mq < 64; mq <<= 1) {
        sum.x += __shfl_xor(sum.x, mq);
        sum.y += __shfl_xor(sum.y, mq);
        sum.z += __shfl_xor(sum.z, mq);
        sum.w += __shfl_xor(sum.w, mq);
    }
    if (l == 0) {
        float4 iv;
        iv.x = 1.f / (sum.x + 1e-16f);
        iv.y = 1.f / (sum.y + 1e-16f);
        iv.z = 1.f / (sum.z + 1e-16f);
        iv.w = 1.f / (sum.w + 1e-16f);
        *(float4*)(inv1 + (size_t)n * 4) = iv;
    }
}

// ---------------- gather1: acc = sum_j p_j * h1_fp16[src_j], *inv + bias + ELU ----------------
// One wave per dst node; lane covers 4 channels (8B fp16 loads). Unroll 4.

__global__ __launch_bounds__(256) void k_gather1(
        const _Float16* __restrict__ h1, const float* __restrict__ alpha,
        const float* __restrict__ inv1, const int* __restrict__ rowptr,
        const int* __restrict__ col, const float* __restrict__ b1,
        float* __restrict__ h2in, int N) {
    int n = blockIdx.x * 4 + (threadIdx.x >> 6);
    if (n >= N) return;
    int l = threadIdx.x & 63;
    int head = l >> 4;
    int beg = __builtin_amdgcn_readfirstlane(rowptr[n]);
    int end = __builtin_amdgcn_readfirstlane(rowptr[n + 1]);
    float4 a0 = make_float4(0.f, 0.f, 0.f, 0.f);
    float4 a1 = make_float4(0.f, 0.f, 0.f, 0.f);
    float4 a2 = make_float4(0.f, 0.f, 0.f, 0.f);
    float4 a3 = make_float4(0.f, 0.f, 0.f, 0.f);
    int j = beg;
    for (; j + 3 < end; j += 4) {
        int s0 = __builtin_amdgcn_readfirstlane(col[j]);
        int s1 = __builtin_amdgcn_readfirstlane(col[j + 1]);
        int s2 = __builtin_amdgcn_readfirstlane(col[j + 2]);
        int s3 = __builtin_amdgcn_readfirstlane(col[j + 3]);
        float p0 = alpha[(size_t)(j + 0) * 4 + head];
        float p1 = alpha[(size_t)(j + 1) * 4 + head];
        float p2 = alpha[(size_t)(j + 2) * 4 + head];
        float p3 = alpha[(size_t)(j + 3) * 4 + head];
        half4v h0 = *((const half4v*)(h1 + (size_t)s0 * 256) + l);
        half4v h1v = *((const half4v*)(h1 + (size_t)s1 * 256) + l);
        half4v h2 = *((const half4v*)(h1 + (size_t)s2 * 256) + l);
        half4v h3 = *((const half4v*)(h1 + (size_t)s3 * 256) + l);
        a0.x = fmaf(p0, (float)h0.x, a0.x); a0.y = fmaf(p0, (float)h0.y, a0.y);
        a0.z = fmaf(p0, (float)h0.z, a0.z); a0.w = fmaf(p0, (float)h0.w, a0.w);
        a1.x = fmaf(p1, (float)h1v.x, a1.x); a1.y = fmaf(p1, (float)h1v.y, a1.y);
        a1.z = fmaf(p1, (float)h1v.z, a1.z); a1.w = fmaf(p1, (float)h1v.w, a1.w);
        a2.x = fmaf(p2, (float)h2.x, a2.x); a2.y = fmaf(p2, (float)h2.y, a2.y);
        a2.z = fmaf(p2, (float)h2.z, a2.z); a2.w = fmaf(p2, (float)h2.w, a2.w);
        a3.x = fmaf(p3, (float)h3.x, a3.x); a3.y = fmaf(p3, (float)h3.y, a3.y);
        a3.z = fmaf(p3, (float)h3.z, a3.z); a3.w = fmaf(p3, (float)h3.w, a3.w);
    }
    for (; j < end; ++j) {
        int s0 = __builtin_amdgcn_readfirstlane(col[j]);
        float p0 = alpha[(size_t)j * 4 + head];
        half4v h0 = *((const half4v*)(h1 + (size_t)s0 * 256) + l);
        a0.x = fmaf(p0, (float)h0.x, a0.x); a0.y = fmaf(p0, (float)h0.y, a0.y);
        a0.z = fmaf(p0, (float)h0.z, a0.z); a0.w = fmaf(p0, (float)h0.w, a0.w);
    }
    a0.x += a1.x + a2.x + a3.x;
    a0.y += a1.y + a2.y + a3.y;
    a0.z += a1.z + a2.z + a3.z;
    a0.w += a1.w + a2.w + a3.w;
    float iv = inv1[(size_t)n * 4 + head];
    float4 bb = *(const float4*)(b1 + l * 4);
    float4 v;
    v.x = a0.x * iv + bb.x;
    v.y = a0.y * iv + bb.y;
    v.z = a0.z * iv + bb.z;
    v.w = a0.w * iv + bb.w;
    v.x = (v.x > 0.f) ? v.x : (__expf(v.x) - 1.f);
    v.y = (v.y > 0.f) ? v.y : (__expf(v.y) - 1.f);
    v.z = (v.z > 0.f) ? v.z : (__expf(v.z) - 1.f);
    v.w = (v.w > 0.f) ? v.w : (__expf(v.w) - 1.f);
    *(float4*)(h2in + (size_t)n * 256 + l * 4) = v;
}

// ---------------- GEMM2: z[N,32] = h2in[N,256] @ W2[256,32], fused alpha2 dots ----------------

__global__ __launch_bounds__(256) void k_gemm2(const float* __restrict__ h,
                                               const float* __restrict__ W2,
                                               const float* __restrict__ asrc,
                                               const float* __restrict__ adst,
                                               float* __restrict__ z, float* __restrict__ as2,
                                               float* __restrict__ ad2, int N) {
    __shared__ float Ws[256 * 32];
    __shared__ float Hs[32 * 68];
    const int tid = threadIdx.x;
    const int r = tid >> 3;
    const int cg = tid & 7;
    const int row0 = blockIdx.x * 32;
    const int row = row0 + r;
    for (int i = tid; i < 256 * 32; i += 256) Ws[i] = W2[i];
    float4 acc = make_float4(0.f, 0.f, 0.f, 0.f);
    for (int k0 = 0; k0 < 256; k0 += 64) {
        __syncthreads();
#pragma unroll
        for (int i = 0; i < 2; ++i) {
            int idx = tid + 256 * i;
            int rr = idx >> 4;
            int c4 = (idx & 15) * 4;
            int rw = row0 + rr;
            float4 v = (rw < N) ? *(const float4*)(h + (size_t)rw * 256 + k0 + c4)
                                : make_float4(0.f, 0.f, 0.f, 0.f);
            *(float4*)(Hs + rr * 68 + c4) = v;
        }
        __syncthreads();
#pragma unroll
        for (int k = 0; k < 64; k += 4) {
            float4 hv = *(const float4*)(Hs + r * 68 + k);
            float4 w0 = *(const float4*)(Ws + (k0 + k) * 32 + cg * 4);
            float4 w1 = *(const float4*)(Ws + (k0 + k + 1) * 32 + cg * 4);
            float4 w2 = *(const float4*)(Ws + (k0 + k + 2) * 32 + cg * 4);
            float4 w3 = *(const float4*)(Ws + (k0 + k + 3) * 32 + cg * 4);
            acc.x = fmaf(hv.x, w0.x, acc.x); acc.y = fmaf(hv.x, w0.y, acc.y);
            acc.z = fmaf(hv.x, w0.z, acc.z); acc.w = fmaf(hv.x, w0.w, acc.w);
            acc.x = fmaf(hv.y, w1.x, acc.x); acc.y = fmaf(hv.y, w1.y, acc.y);
            acc.z = fmaf(hv.y, w1.z, acc.z); acc.w = fmaf(hv.y, w1.w, acc.w);
            acc.x = fmaf(hv.z, w2.x, acc.x); acc.y = fmaf(hv.z, w2.y, acc.y);
            acc.z = fmaf(hv.z, w2.z, acc.z); acc.w = fmaf(hv.z, w2.w, acc.w);
            acc.x = fmaf(hv.w, w3.x, acc.x); acc.y = fmaf(hv.w, w3.y, acc.y);
            acc.z = fmaf(hv.w, w3.z, acc.z); acc.w = fmaf(hv.w, w3.w, acc.w);
        }
    }
    float4 a4 = *(const float4*)(asrc + cg * 4);
    float4 d4 = *(const float4*)(adst + cg * 4);
    float va = acc.x * a4.x + acc.y * a4.y + acc.z * a4.z + acc.w * a4.w;
    float vd = acc.x * d4.x + acc.y * d4.y + acc.z * d4.z + acc.w * d4.w;
#pragma unroll
    for (int mq = 1; mq < 8; mq <<= 1) {
        va += __shfl_xor(va, mq);
        vd += __shfl_xor(vd, mq);
    }
    if (row < N) {
        *(float4*)(z + (size_t)row * 32 + cg * 4) = acc;
        if (cg == 0) {
            as2[row] = va;
            ad2[row] = vd;
        }
    }
}

// ---------------- edge2: unnormalized softmax weights, 1 head ----------------

__global__ void k_edge2(const float* __restrict__ as2, const float* __restrict__ ad2,
                        const int* __restrict__ rowptr, const int* __restrict__ col,
                        float* __restrict__ alpha2, float* __restrict__ inv2, int N) {
    int n = blockIdx.x * 4 + (threadIdx.x >> 6);
    if (n >= N) return;
    int l = threadIdx.x & 63;
    int beg = __builtin_amdgcn_readfirstlane(rowptr[n]);
    int end = __builtin_amdgcn_readfirstlane(rowptr[n + 1]);
    float adn = ad2[n];
    float sum = 0.f;
    for (int j = beg + l; j < end; j += 64) {
        int src = col[j];
        float e = as2[src] + adn;
        e = fmaxf(e, NEG_SLOPE * e);
        float p = __expf(e);
        alpha2[j] = p;
        sum += p;
    }
#pragma unroll
    for (int mq = 1; mq < 64; mq <<= 1) sum += __shfl_xor(sum, mq);
    if (l == 0) inv2[n] = 1.f / (sum + 1e-16f);
}

// ---------------- gather2: out = (sum_j p_j * z[src_j]) * inv + b2 ----------------

__global__ void k_gather2(const float* __restrict__ z, const float* __restrict__ alpha2,
                          const float* __restrict__ inv2, const int* __restrict__ rowptr,
                          const int* __restrict__ col, const float* __restrict__ b2,
                          float* __restrict__ out, int N) {
    int n = blockIdx.x * 4 + (threadIdx.x >> 6);
    if (n >= N) return;
    int l = threadIdx.x & 63;
    int eo = l >> 3;
    int cg = l & 7;
    int beg = __builtin_amdgcn_readfirstlane(rowptr[n]);
    int end = __builtin_amdgcn_readfirstlane(rowptr[n + 1]);
    float4 acc = make_float4(0.f, 0.f, 0.f, 0.f);
    for (int j0 = beg; j0 < end; j0 += 8) {
        int idx = j0 + eo;
        bool valid = idx < end;
        int idc = valid ? idx : (end - 1);
        int src = col[idc];
        float p = valid ? alpha2[idc] : 0.f;
        float4 zv = *(const float4*)(z + (size_t)src * 32 + cg * 4);
        acc.x = fmaf(p, zv.x, acc.x); acc.y = fmaf(p, zv.y, acc.y);
        acc.z = fmaf(p, zv.z, acc.z); acc.w = fmaf(p, zv.w, acc.w);
    }
#pragma unroll
    for (int mq = 8; mq < 64; mq <<= 1) {
        acc.x += __shfl_xor(acc.x, mq);
        acc.y += __shfl_xor(acc.y, mq);
        acc.z += __shfl_xor(acc.z, mq);
        acc.w += __shfl_xor(acc.w, mq);
    }
    if (eo == 0) {
        float iv = inv2[n];
        float4 bb = *(const float4*)(b2 + cg * 4);
        float4 v;
        v.x = acc.x * iv + bb.x;
        v.y = acc.y * iv + bb.y;
        v.z = acc.z * iv + bb.z;
        v.w = acc.w * iv + bb.w;
        *(float4*)(out + (size_t)n * 32 + cg * 4) = v;
    }
}

// ---------------- launch ----------------

extern "C" void kernel_launch(void* const* d_in, const int* in_sizes, int n_in,
                              void* d_out, int out_size, void* d_ws, size_t ws_size,
                              hipStream_t stream) {
    const float* x    = (const float*)d_in[0];
    const int*   ei   = (const int*)d_in[1];
    const float* W1   = (const float*)d_in[2];
    const float* a_s1 = (const float*)d_in[3];
    const float* a_d1 = (const float*)d_in[4];
    const float* b1   = (const float*)d_in[5];
    const float* W2   = (const float*)d_in[6];
    const float* a_s2 = (const float*)d_in[7];
    const float* a_d2 = (const float*)d_in[8];
    const float* b2   = (const float*)d_in[9];
    float* out = (float*)d_out;

    const int N = in_sizes[0] / 256;
    const int E = in_sizes[1] / 2;
    const int EP = E + N;  // with self-loops
    const int* srcIdx = ei;
    const int* dstIdx = ei + E;

    char* ws = (char*)d_ws;
    size_t off = 0;
    auto alloc = [&](size_t bytes) {
        void* p = ws + off;
        off += (bytes + 255) & ~(size_t)255;
        return p;
    };
    _Float16* h1  = (_Float16*)alloc((size_t)N * 256 * 2);  // fp16 gather table
    float* h2in   = (float*)alloc((size_t)N * 256 * 4);
    float* z      = (float*)alloc((size_t)N * 32 * 4);
    float* alpha  = (float*)alloc((size_t)EP * 16);         // layer1 float4/edge; reused layer2
    float* as1    = (float*)alloc((size_t)N * 16);          // reused as as2
    float* ad1    = (float*)alloc((size_t)N * 16);          // reused as ad2
    float* inv1   = (float*)alloc((size_t)N * 16);          // reused as inv2
    int*   hist   = (int*)alloc((size_t)N * 4);
    int*   cursor = (int*)alloc((size_t)N * 4);
    int*   rowptr = (int*)alloc((size_t)(N + 1) * 4);
    int*   col    = (int*)alloc((size_t)EP * 4);

    float* alpha2 = alpha;
    float* as2    = as1;
    float* ad2    = ad1;
    float* inv2   = inv1;

    // CSR build (dst-sorted adjacency, self-loops included)
    k_init<<<(N + 255) / 256, 256, 0, stream>>>(hist, N);
    k_count<<<(E + 255) / 256, 256, 0, stream>>>(dstIdx, hist, E);
    k_scan<<<1, 1024, 0, stream>>>(hist, rowptr, cursor, col, N);
    k_scatter<<<(E + 255) / 256, 256, 0, stream>>>(srcIdx, dstIdx, cursor, col, E);

    // layer 1
    dim3 g1(2, (N + 127) / 128);
    k_gemm1<<<g1, 256, 0, stream>>>(x, W1, a_s1, a_d1, h1, as1, ad1, N);
    k_edge1<<<(N + 3) / 4, 256, 0, stream>>>(as1, ad1, rowptr, col, alpha, inv1, N);
    k_gather1<<<(N + 3) / 4, 256, 0, stream>>>(h1, alpha, inv1, rowptr, col, b1, h2in, N);

    // layer 2
    k_gemm2<<<(N + 31) / 32, 256, 0, stream>>>(h2in, W2, a_s2, a_d2, z, as2, ad2, N);
    k_edge2<<<(N + 3) / 4, 256, 0, stream>>>(as2, ad2, rowptr, col, alpha2, inv2, N);
    k_gather2<<<(N + 3) / 4, 256, 0, stream>>>(z, alpha2, inv2, rowptr, col, b2, out, N);
}

// Round 5
// 372.246 us; speedup vs baseline: 1.5051x; 1.2115x over previous
//
#include <hip/hip_runtime.h>

#define NEG_SLOPE 0.2f

typedef short bf16x8 __attribute__((ext_vector_type(8)));
typedef float f32x4 __attribute__((ext_vector_type(4)));
typedef _Float16 half4v __attribute__((ext_vector_type(4)));

// split fp32 into hi (truncated bf16) + lo (RNE bf16 of remainder): x ~= hi + lo, err ~2^-17*x
__device__ inline void split_bf16(float x, short& hi, short& lo) {
    unsigned xb = __float_as_uint(x);
    hi = (short)(xb >> 16);
    float hif = __uint_as_float(xb & 0xFFFF0000u);
    float rem = x - hif;
    unsigned rb = __float_as_uint(rem);
    unsigned r = rb + 0x7FFFu + ((rb >> 16) & 1u);
    lo = (short)(r >> 16);
}

// ---------------- CSR build ----------------

__global__ void k_init(int* hist, int N) {
    int i = blockIdx.x * 256 + threadIdx.x;
    if (i < N) hist[i] = 1;  // self-loop pre-counted
}

__global__ void k_count(const int* __restrict__ dst, int* hist, int E) {
    int i = blockIdx.x * 256 + threadIdx.x;
    if (i < E) atomicAdd(&hist[dst[i]], 1);
}

// phase 1: per-block (256-elt) sums of hist
__global__ void k_bsum(const int* __restrict__ hist, int* __restrict__ bsum, int n) {
    const int tid = threadIdx.x;
    const int lane = tid & 63;
    const int wave = tid >> 6;
    int idx = blockIdx.x * 256 + tid;
    int v = (idx < n) ? hist[idx] : 0;
#pragma unroll
    for (int mq = 1; mq < 64; mq <<= 1) v += __shfl_xor(v, mq);
    __shared__ int ws[4];
    if (lane == 0) ws[wave] = v;
    __syncthreads();
    if (tid == 0) bsum[blockIdx.x] = ws[0] + ws[1] + ws[2] + ws[3];
}

// phase 2: single small block scans the block sums (chunked with carry), writes rowptr[n]=total
__global__ void k_scan_bsum(const int* __restrict__ bsum, int* __restrict__ boff,
                            int* __restrict__ rowptr, int nb, int n) {
    __shared__ int ws[4];
    const int tid = threadIdx.x;
    const int lane = tid & 63;
    const int wave = tid >> 6;
    int carry = 0;  // identical in all threads
    for (int base = 0; base < nb; base += 256) {
        int i = base + tid;
        int v = (i < nb) ? bsum[i] : 0;
        int incl = v;
#pragma unroll
        for (int off = 1; off < 64; off <<= 1) {
            int t = __shfl_up(incl, off);
            if (lane >= off) incl += t;
        }
        if (lane == 63) ws[wave] = incl;
        __syncthreads();
        int wpre = 0, total = 0;
#pragma unroll
        for (int w = 0; w < 4; ++w) {
            int s = ws[w];
            if (w < wave) wpre += s;
            total += s;
        }
        if (i < nb) boff[i] = carry + wpre + incl - v;
        carry += total;
        __syncthreads();
    }
    if (tid == 0) rowptr[n] = carry;
}

// phase 3: intra-block exclusive scan + block offset; write rowptr/col-selfloop/cursor
__global__ void k_scan_final(const int* __restrict__ hist, const int* __restrict__ boff,
                             int* __restrict__ rowptr, int* __restrict__ cursor,
                             int* __restrict__ col, int n) {
    const int tid = threadIdx.x;
    const int lane = tid & 63;
    const int wave = tid >> 6;
    int idx = blockIdx.x * 256 + tid;
    int v = (idx < n) ? hist[idx] : 0;
    int incl = v;
#pragma unroll
    for (int off = 1; off < 64; off <<= 1) {
        int t = __shfl_up(incl, off);
        if (lane >= off) incl += t;
    }
    __shared__ int ws[4];
    if (lane == 63) ws[wave] = incl;
    __syncthreads();
    int wpre = 0;
#pragma unroll
    for (int w = 0; w < 4; ++w)
        if (w < wave) wpre += ws[w];
    int excl = boff[blockIdx.x] + wpre + incl - v;
    if (idx < n) {
        rowptr[idx] = excl;
        col[excl] = idx;        // self-loop in slot 0 of each segment
        cursor[idx] = excl + 1;
    }
}

__global__ void k_scatter(const int* __restrict__ src, const int* __restrict__ dst,
                          int* cursor, int* col, int E) {
    int i = blockIdx.x * 256 + threadIdx.x;
    if (i < E) {
        int p = atomicAdd(&cursor[dst[i]], 1);
        col[p] = src[i];
    }
}

// ---------------- GEMM1 (split-bf16 MFMA): h1[N,256](fp16) = x @ W1, fused alpha1 dots ----------

__global__ __launch_bounds__(256) void k_gemm1(
        const float* __restrict__ x, const float* __restrict__ W,
        const float* __restrict__ a_src, const float* __restrict__ a_dst,
        _Float16* __restrict__ h1, float* __restrict__ as1, float* __restrict__ ad1, int N) {
    __shared__ short Ah[128 * 40];  // [m][k], stride 40 (pad: conflict-free b128)
    __shared__ short Al[128 * 40];
    __shared__ short Bh[128 * 40];  // [n][k], stride 40
    __shared__ short Bl[128 * 40];
    const int tid = threadIdx.x;
    const int lane = tid & 63;
    const int wave = tid >> 6;
    const int wr = wave & 1, wc = wave >> 1;
    const int row0 = blockIdx.y * 128;
    const int col0 = blockIdx.x * 128;
    const int m15 = lane & 15, quad = lane >> 4;

    f32x4 acc[4][4] = {};

    const int arow = tid >> 1;
    const int akseg = (tid & 1) * 16;
    const int bcol = tid & 127;
    const int bkh = (tid >> 7) * 16;

    for (int k0 = 0; k0 < 256; k0 += 32) {
        {
            int row = row0 + arow;
            float vals[16];
            if (row < N) {
#pragma unroll
                for (int i = 0; i < 4; ++i) {
                    float4 v = *(const float4*)(x + (size_t)row * 256 + k0 + akseg + i * 4);
                    vals[i * 4 + 0] = v.x; vals[i * 4 + 1] = v.y;
                    vals[i * 4 + 2] = v.z; vals[i * 4 + 3] = v.w;
                }
            } else {
#pragma unroll
                for (int i = 0; i < 16; ++i) vals[i] = 0.f;
            }
            short hbuf[16], lbuf[16];
#pragma unroll
            for (int i = 0; i < 16; ++i) split_bf16(vals[i], hbuf[i], lbuf[i]);
            *(bf16x8*)&Ah[arow * 40 + akseg]     = *(bf16x8*)&hbuf[0];
            *(bf16x8*)&Ah[arow * 40 + akseg + 8] = *(bf16x8*)&hbuf[8];
            *(bf16x8*)&Al[arow * 40 + akseg]     = *(bf16x8*)&lbuf[0];
            *(bf16x8*)&Al[arow * 40 + akseg + 8] = *(bf16x8*)&lbuf[8];
        }
        {
            float vals[16];
#pragma unroll
            for (int k = 0; k < 16; ++k)
                vals[k] = W[(size_t)(k0 + bkh + k) * 256 + col0 + bcol];
            short hbuf[16], lbuf[16];
#pragma unroll
            for (int i = 0; i < 16; ++i) split_bf16(vals[i], hbuf[i], lbuf[i]);
            *(bf16x8*)&Bh[bcol * 40 + bkh]     = *(bf16x8*)&hbuf[0];
            *(bf16x8*)&Bh[bcol * 40 + bkh + 8] = *(bf16x8*)&hbuf[8];
            *(bf16x8*)&Bl[bcol * 40 + bkh]     = *(bf16x8*)&lbuf[0];
            *(bf16x8*)&Bl[bcol * 40 + bkh + 8] = *(bf16x8*)&lbuf[8];
        }
        __syncthreads();
        bf16x8 ah[4], al[4];
#pragma unroll
        for (int mt = 0; mt < 4; ++mt) {
            int m = wr * 64 + mt * 16 + m15;
            ah[mt] = *(const bf16x8*)&Ah[m * 40 + quad * 8];
            al[mt] = *(const bf16x8*)&Al[m * 40 + quad * 8];
        }
#pragma unroll
        for (int nt = 0; nt < 4; ++nt) {
            int nn = wc * 64 + nt * 16 + m15;
            bf16x8 bh = *(const bf16x8*)&Bh[nn * 40 + quad * 8];
            bf16x8 bl = *(const bf16x8*)&Bl[nn * 40 + quad * 8];
#pragma unroll
            for (int mt = 0; mt < 4; ++mt) {
                acc[mt][nt] = __builtin_amdgcn_mfma_f32_16x16x32_bf16(ah[mt], bh, acc[mt][nt], 0, 0, 0);
                acc[mt][nt] = __builtin_amdgcn_mfma_f32_16x16x32_bf16(ah[mt], bl, acc[mt][nt], 0, 0, 0);
                acc[mt][nt] = __builtin_amdgcn_mfma_f32_16x16x32_bf16(al[mt], bh, acc[mt][nt], 0, 0, 0);
            }
        }
        __syncthreads();
    }
    const int head = (col0 >> 6) + wc;
#pragma unroll
    for (int mt = 0; mt < 4; ++mt) {
        float va[4] = {0.f, 0.f, 0.f, 0.f};
        float vd[4] = {0.f, 0.f, 0.f, 0.f};
#pragma unroll
        for (int nt = 0; nt < 4; ++nt) {
            int colg = col0 + wc * 64 + nt * 16 + m15;
            float asv = a_src[colg];
            float adv = a_dst[colg];
#pragma unroll
            for (int r = 0; r < 4; ++r) {
                float accv = acc[mt][nt][r];
                int row = row0 + wr * 64 + mt * 16 + quad * 4 + r;
                if (row < N) h1[(size_t)row * 256 + colg] = (_Float16)accv;
                va[r] = fmaf(accv, asv, va[r]);
                vd[r] = fmaf(accv, adv, vd[r]);
            }
        }
#pragma unroll
        for (int r = 0; r < 4; ++r) {
#pragma unroll
            for (int mq = 1; mq < 16; mq <<= 1) {
                va[r] += __shfl_xor(va[r], mq);
                vd[r] += __shfl_xor(vd[r], mq);
            }
            int row = row0 + wr * 64 + mt * 16 + quad * 4 + r;
            if (m15 == 0 && row < N) {
                as1[(size_t)row * 4 + head] = va[r];
                ad1[(size_t)row * 4 + head] = vd[r];
            }
        }
    }
}

// ---------------- edge1: unnormalized softmax weights (all 4 heads) ----------------

__global__ void k_edge1(const float* __restrict__ as1, const float* __restrict__ ad1,
                        const int* __restrict__ rowptr, const int* __restrict__ col,
                        float* __restrict__ alpha, float* __restrict__ inv1, int N) {
    int n = blockIdx.x * 4 + (threadIdx.x >> 6);
    if (n >= N) return;
    int l = threadIdx.x & 63;
    int beg = __builtin_amdgcn_readfirstlane(rowptr[n]);
    int end = __builtin_amdgcn_readfirstlane(rowptr[n + 1]);
    float4 ad = *(const float4*)(ad1 + (size_t)n * 4);
    float4 sum = make_float4(0.f, 0.f, 0.f, 0.f);
    for (int j = beg + l; j < end; j += 64) {
        int src = col[j];
        float4 as = *(const float4*)(as1 + (size_t)src * 4);
        float4 e;
        e.x = as.x + ad.x; e.x = fmaxf(e.x, NEG_SLOPE * e.x);
        e.y = as.y + ad.y; e.y = fmaxf(e.y, NEG_SLOPE * e.y);
        e.z = as.z + ad.z; e.z = fmaxf(e.z, NEG_SLOPE * e.z);
        e.w = as.w + ad.w; e.w = fmaxf(e.w, NEG_SLOPE * e.w);
        float4 p;
        p.x = __expf(e.x); p.y = __expf(e.y); p.z = __expf(e.z); p.w = __expf(e.w);
        *(float4*)(alpha + (size_t)j * 4) = p;
        sum.x += p.x; sum.y += p.y; sum.z += p.z; sum.w += p.w;
    }
#pragma unroll
    for (int mq = 1; mq < 64; mq <<= 1) {
        sum.x += __shfl_xor(sum.x, mq);
        sum.y += __shfl_xor(sum.y, mq);
        sum.z += __shfl_xor(sum.z, mq);
        sum.w += __shfl_xor(sum.w, mq);
    }
    if (l == 0) {
        float4 iv;
        iv.x = 1.f / (sum.x + 1e-16f);
        iv.y = 1.f / (sum.y + 1e-16f);
        iv.z = 1.f / (sum.z + 1e-16f);
        iv.w = 1.f / (sum.w + 1e-16f);
        *(float4*)(inv1 + (size_t)n * 4) = iv;
    }
}

// ---------------- gather1: acc = sum_j p_j * h1_fp16[src_j], *inv + bias + ELU ----------------

__global__ __launch_bounds__(256) void k_gather1(
        const _Float16* __restrict__ h1, const float* __restrict__ alpha,
        const float* __restrict__ inv1, const int* __restrict__ rowptr,
        const int* __restrict__ col, const float* __restrict__ b1,
        float* __restrict__ h2in, int N) {
    int n = blockIdx.x * 4 + (threadIdx.x >> 6);
    if (n >= N) return;
    int l = threadIdx.x & 63;
    int head = l >> 4;
    int beg = __builtin_amdgcn_readfirstlane(rowptr[n]);
    int end = __builtin_amdgcn_readfirstlane(rowptr[n + 1]);
    float4 a0 = make_float4(0.f, 0.f, 0.f, 0.f);
    float4 a1 = make_float4(0.f, 0.f, 0.f, 0.f);
    float4 a2 = make_float4(0.f, 0.f, 0.f, 0.f);
    float4 a3 = make_float4(0.f, 0.f, 0.f, 0.f);
    int j = beg;
    for (; j + 3 < end; j += 4) {
        int s0 = __builtin_amdgcn_readfirstlane(col[j]);
        int s1 = __builtin_amdgcn_readfirstlane(col[j + 1]);
        int s2 = __builtin_amdgcn_readfirstlane(col[j + 2]);
        int s3 = __builtin_amdgcn_readfirstlane(col[j + 3]);
        float p0 = alpha[(size_t)(j + 0) * 4 + head];
        float p1 = alpha[(size_t)(j + 1) * 4 + head];
        float p2 = alpha[(size_t)(j + 2) * 4 + head];
        float p3 = alpha[(size_t)(j + 3) * 4 + head];
        half4v h0 = *((const half4v*)(h1 + (size_t)s0 * 256) + l);
        half4v h1v = *((const half4v*)(h1 + (size_t)s1 * 256) + l);
        half4v h2 = *((const half4v*)(h1 + (size_t)s2 * 256) + l);
        half4v h3 = *((const half4v*)(h1 + (size_t)s3 * 256) + l);
        a0.x = fmaf(p0, (float)h0.x, a0.x); a0.y = fmaf(p0, (float)h0.y, a0.y);
        a0.z = fmaf(p0, (float)h0.z, a0.z); a0.w = fmaf(p0, (float)h0.w, a0.w);
        a1.x = fmaf(p1, (float)h1v.x, a1.x); a1.y = fmaf(p1, (float)h1v.y, a1.y);
        a1.z = fmaf(p1, (float)h1v.z, a1.z); a1.w = fmaf(p1, (float)h1v.w, a1.w);
        a2.x = fmaf(p2, (float)h2.x, a2.x); a2.y = fmaf(p2, (float)h2.y, a2.y);
        a2.z = fmaf(p2, (float)h2.z, a2.z); a2.w = fmaf(p2, (float)h2.w, a2.w);
        a3.x = fmaf(p3, (float)h3.x, a3.x); a3.y = fmaf(p3, (float)h3.y, a3.y);
        a3.z = fmaf(p3, (float)h3.z, a3.z); a3.w = fmaf(p3, (float)h3.w, a3.w);
    }
    for (; j < end; ++j) {
        int s0 = __builtin_amdgcn_readfirstlane(col[j]);
        float p0 = alpha[(size_t)j * 4 + head];
        half4v h0 = *((const half4v*)(h1 + (size_t)s0 * 256) + l);
        a0.x = fmaf(p0, (float)h0.x, a0.x); a0.y = fmaf(p0, (float)h0.y, a0.y);
        a0.z = fmaf(p0, (float)h0.z, a0.z); a0.w = fmaf(p0, (float)h0.w, a0.w);
    }
    a0.x += a1.x + a2.x + a3.x;
    a0.y += a1.y + a2.y + a3.y;
    a0.z += a1.z + a2.z + a3.z;
    a0.w += a1.w + a2.w + a3.w;
    float iv = inv1[(size_t)n * 4 + head];
    float4 bb = *(const float4*)(b1 + l * 4);
    float4 v;
    v.x = a0.x * iv + bb.x;
    v.y = a0.y * iv + bb.y;
    v.z = a0.z * iv + bb.z;
    v.w = a0.w * iv + bb.w;
    v.x = (v.x > 0.f) ? v.x : (__expf(v.x) - 1.f);
    v.y = (v.y > 0.f) ? v.y : (__expf(v.y) - 1.f);
    v.z = (v.z > 0.f) ? v.z : (__expf(v.z) - 1.f);
    v.w = (v.w > 0.f) ? v.w : (__expf(v.w) - 1.f);
    *(float4*)(h2in + (size_t)n * 256 + l * 4) = v;
}

// ---------------- GEMM2: z[N,32] = h2in[N,256] @ W2[256,32], fused alpha2 dots ----------------

__global__ __launch_bounds__(256) void k_gemm2(const float* __restrict__ h,
                                               const float* __restrict__ W2,
                                               const float* __restrict__ asrc,
                                               const float* __restrict__ adst,
                                               float* __restrict__ z, float* __restrict__ as2,
                                               float* __restrict__ ad2, int N) {
    __shared__ float Ws[256 * 32];
    __shared__ float Hs[32 * 68];
    const int tid = threadIdx.x;
    const int r = tid >> 3;
    const int cg = tid & 7;
    const int row0 = blockIdx.x * 32;
    const int row = row0 + r;
    for (int i = tid; i < 256 * 32; i += 256) Ws[i] = W2[i];
    float4 acc = make_float4(0.f, 0.f, 0.f, 0.f);
    for (int k0 = 0; k0 < 256; k0 += 64) {
        __syncthreads();
#pragma unroll
        for (int i = 0; i < 2; ++i) {
            int idx = tid + 256 * i;
            int rr = idx >> 4;
            int c4 = (idx & 15) * 4;
            int rw = row0 + rr;
            float4 v = (rw < N) ? *(const float4*)(h + (size_t)rw * 256 + k0 + c4)
                                : make_float4(0.f, 0.f, 0.f, 0.f);
            *(float4*)(Hs + rr * 68 + c4) = v;
        }
        __syncthreads();
#pragma unroll
        for (int k = 0; k < 64; k += 4) {
            float4 hv = *(const float4*)(Hs + r * 68 + k);
            float4 w0 = *(const float4*)(Ws + (k0 + k) * 32 + cg * 4);
            float4 w1 = *(const float4*)(Ws + (k0 + k + 1) * 32 + cg * 4);
            float4 w2 = *(const float4*)(Ws + (k0 + k + 2) * 32 + cg * 4);
            float4 w3 = *(const float4*)(Ws + (k0 + k + 3) * 32 + cg * 4);
            acc.x = fmaf(hv.x, w0.x, acc.x); acc.y = fmaf(hv.x, w0.y, acc.y);
            acc.z = fmaf(hv.x, w0.z, acc.z); acc.w = fmaf(hv.x, w0.w, acc.w);
            acc.x = fmaf(hv.y, w1.x, acc.x); acc.y = fmaf(hv.y, w1.y, acc.y);
            acc.z = fmaf(hv.y, w1.z, acc.z); acc.w = fmaf(hv.y, w1.w, acc.w);
            acc.x = fmaf(hv.z, w2.x, acc.x); acc.y = fmaf(hv.z, w2.y, acc.y);
            acc.z = fmaf(hv.z, w2.z, acc.z); acc.w = fmaf(hv.z, w2.w, acc.w);
            acc.x = fmaf(hv.w, w3.x, acc.x); acc.y = fmaf(hv.w, w3.y, acc.y);
            acc.z = fmaf(hv.w, w3.z, acc.z); acc.w = fmaf(hv.w, w3.w, acc.w);
        }
    }
    float4 a4 = *(const float4*)(asrc + cg * 4);
    float4 d4 = *(const float4*)(adst + cg * 4);
    float va = acc.x * a4.x + acc.y * a4.y + acc.z * a4.z + acc.w * a4.w;
    float vd = acc.x * d4.x + acc.y * d4.y + acc.z * d4.z + acc.w * d4.w;
#pragma unroll
    for (int mq = 1; mq < 8; mq <<= 1) {
        va += __shfl_xor(va, mq);
        vd += __shfl_xor(vd, mq);
    }
    if (row < N) {
        *(float4*)(z + (size_t)row * 32 + cg * 4) = acc;
        if (cg == 0) {
            as2[row] = va;
            ad2[row] = vd;
        }
    }
}

// ---------------- edge2: unnormalized softmax weights, 1 head ----------------

__global__ void k_edge2(const float* __restrict__ as2, const float* __restrict__ ad2,
                        const int* __restrict__ rowptr, const int* __restrict__ col,
                        float* __restrict__ alpha2, float* __restrict__ inv2, int N) {
    int n = blockIdx.x * 4 + (threadIdx.x >> 6);
    if (n >= N) return;
    int l = threadIdx.x & 63;
    int beg = __builtin_amdgcn_readfirstlane(rowptr[n]);
    int end = __builtin_amdgcn_readfirstlane(rowptr[n + 1]);
    float adn = ad2[n];
    float sum = 0.f;
    for (int j = beg + l; j < end; j += 64) {
        int src = col[j];
        float e = as2[src] + adn;
        e = fmaxf(e, NEG_SLOPE * e);
        float p = __expf(e);
        alpha2[j] = p;
        sum += p;
    }
#pragma unroll
    for (int mq = 1; mq < 64; mq <<= 1) sum += __shfl_xor(sum, mq);
    if (l == 0) inv2[n] = 1.f / (sum + 1e-16f);
}

// ---------------- gather2: out = (sum_j p_j * z[src_j]) * inv + b2 ----------------

__global__ void k_gather2(const float* __restrict__ z, const float* __restrict__ alpha2,
                          const float* __restrict__ inv2, const int* __restrict__ rowptr,
                          const int* __restrict__ col, const float* __restrict__ b2,
                          float* __restrict__ out, int N) {
    int n = blockIdx.x * 4 + (threadIdx.x >> 6);
    if (n >= N) return;
    int l = threadIdx.x & 63;
    int eo = l >> 3;
    int cg = l & 7;
    int beg = __builtin_amdgcn_readfirstlane(rowptr[n]);
    int end = __builtin_amdgcn_readfirstlane(rowptr[n + 1]);
    float4 acc = make_float4(0.f, 0.f, 0.f, 0.f);
    for (int j0 = beg; j0 < end; j0 += 8) {
        int idx = j0 + eo;
        bool valid = idx < end;
        int idc = valid ? idx : (end - 1);
        int src = col[idc];
        float p = valid ? alpha2[idc] : 0.f;
        float4 zv = *(const float4*)(z + (size_t)src * 32 + cg * 4);
        acc.x = fmaf(p, zv.x, acc.x); acc.y = fmaf(p, zv.y, acc.y);
        acc.z = fmaf(p, zv.z, acc.z); acc.w = fmaf(p, zv.w, acc.w);
    }
#pragma unroll
    for (int mq = 8; mq < 64; mq <<= 1) {
        acc.x += __shfl_xor(acc.x, mq);
        acc.y += __shfl_xor(acc.y, mq);
        acc.z += __shfl_xor(acc.z, mq);
        acc.w += __shfl_xor(acc.w, mq);
    }
    if (eo == 0) {
        float iv = inv2[n];
        float4 bb = *(const float4*)(b2 + cg * 4);
        float4 v;
        v.x = acc.x * iv + bb.x;
        v.y = acc.y * iv + bb.y;
        v.z = acc.z * iv + bb.z;
        v.w = acc.w * iv + bb.w;
        *(float4*)(out + (size_t)n * 32 + cg * 4) = v;
    }
}

// ---------------- launch ----------------

extern "C" void kernel_launch(void* const* d_in, const int* in_sizes, int n_in,
                              void* d_out, int out_size, void* d_ws, size_t ws_size,
                              hipStream_t stream) {
    const float* x    = (const float*)d_in[0];
    const int*   ei   = (const int*)d_in[1];
    const float* W1   = (const float*)d_in[2];
    const float* a_s1 = (const float*)d_in[3];
    const float* a_d1 = (const float*)d_in[4];
    const float* b1   = (const float*)d_in[5];
    const float* W2   = (const float*)d_in[6];
    const float* a_s2 = (const float*)d_in[7];
    const float* a_d2 = (const float*)d_in[8];
    const float* b2   = (const float*)d_in[9];
    float* out = (float*)d_out;

    const int N = in_sizes[0] / 256;
    const int E = in_sizes[1] / 2;
    const int EP = E + N;  // with self-loops
    const int* srcIdx = ei;
    const int* dstIdx = ei + E;
    const int NB = (N + 255) / 256;

    char* ws = (char*)d_ws;
    size_t off = 0;
    auto alloc = [&](size_t bytes) {
        void* p = ws + off;
        off += (bytes + 255) & ~(size_t)255;
        return p;
    };
    _Float16* h1  = (_Float16*)alloc((size_t)N * 256 * 2);  // fp16 gather table
    float* h2in   = (float*)alloc((size_t)N * 256 * 4);
    float* z      = (float*)alloc((size_t)N * 32 * 4);
    float* alpha  = (float*)alloc((size_t)EP * 16);         // layer1 float4/edge; reused layer2
    float* as1    = (float*)alloc((size_t)N * 16);          // reused as as2
    float* ad1    = (float*)alloc((size_t)N * 16);          // reused as ad2
    float* inv1   = (float*)alloc((size_t)N * 16);          // reused as inv2
    int*   hist   = (int*)alloc((size_t)N * 4);
    int*   cursor = (int*)alloc((size_t)N * 4);
    int*   rowptr = (int*)alloc((size_t)(N + 1) * 4);
    int*   col    = (int*)alloc((size_t)EP * 4);
    int*   bsum   = (int*)alloc((size_t)NB * 4);
    int*   boff   = (int*)alloc((size_t)NB * 4);

    float* alpha2 = alpha;
    float* as2    = as1;
    float* ad2    = ad1;
    float* inv2   = inv1;

    // CSR build (dst-sorted adjacency, self-loops included), parallel 3-phase scan
    k_init<<<NB, 256, 0, stream>>>(hist, N);
    k_count<<<(E + 255) / 256, 256, 0, stream>>>(dstIdx, hist, E);
    k_bsum<<<NB, 256, 0, stream>>>(hist, bsum, N);
    k_scan_bsum<<<1, 256, 0, stream>>>(bsum, boff, rowptr, NB, N);
    k_scan_final<<<NB, 256, 0, stream>>>(hist, boff, rowptr, cursor, col, N);
    k_scatter<<<(E + 255) / 256, 256, 0, stream>>>(srcIdx, dstIdx, cursor, col, E);

    // layer 1
    dim3 g1(2, (N + 127) / 128);
    k_gemm1<<<g1, 256, 0, stream>>>(x, W1, a_s1, a_d1, h1, as1, ad1, N);
    k_edge1<<<(N + 3) / 4, 256, 0, stream>>>(as1, ad1, rowptr, col, alpha, inv1, N);
    k_gather1<<<(N + 3) / 4, 256, 0, stream>>>(h1, alpha, inv1, rowptr, col, b1, h2in, N);

    // layer 2
    k_gemm2<<<(N + 31) / 32, 256, 0, stream>>>(h2in, W2, a_s2, a_d2, z, as2, ad2, N);
    k_edge2<<<(N + 3) / 4, 256, 0, stream>>>(as2, ad2, rowptr, col, alpha2, inv2, N);
    k_gather2<<<(N + 3) / 4, 256, 0, stream>>>(z, alpha2, inv2, rowptr, col, b2, out, N);
}

// Round 6
// 352.372 us; speedup vs baseline: 1.5900x; 1.0564x over previous
//
#include <hip/hip_runtime.h>

#define NEG_SLOPE 0.2f

typedef short bf16x8 __attribute__((ext_vector_type(8)));
typedef float f32x4 __attribute__((ext_vector_type(4)));
typedef _Float16 half4v __attribute__((ext_vector_type(4)));

// split fp32 into hi (truncated bf16) + lo (RNE bf16 of remainder): x ~= hi + lo, err ~2^-17*x
__device__ inline void split_bf16(float x, short& hi, short& lo) {
    unsigned xb = __float_as_uint(x);
    hi = (short)(xb >> 16);
    float hif = __uint_as_float(xb & 0xFFFF0000u);
    float rem = x - hif;
    unsigned rb = __float_as_uint(rem);
    unsigned r = rb + 0x7FFFu + ((rb >> 16) & 1u);
    lo = (short)(r >> 16);
}

// ---------------- CSR build ----------------

__global__ void k_init(int* hist, int N) {
    int i = blockIdx.x * 256 + threadIdx.x;
    if (i < N) hist[i] = 1;  // self-loop pre-counted
}

__global__ void k_count(const int* __restrict__ dst, int* hist, int E) {
    int i = blockIdx.x * 256 + threadIdx.x;
    if (i < E) atomicAdd(&hist[dst[i]], 1);
}

// phase 1: per-block (256-elt) sums of hist
__global__ void k_bsum(const int* __restrict__ hist, int* __restrict__ bsum, int n) {
    const int tid = threadIdx.x;
    const int lane = tid & 63;
    const int wave = tid >> 6;
    int idx = blockIdx.x * 256 + tid;
    int v = (idx < n) ? hist[idx] : 0;
#pragma unroll
    for (int mq = 1; mq < 64; mq <<= 1) v += __shfl_xor(v, mq);
    __shared__ int ws[4];
    if (lane == 0) ws[wave] = v;
    __syncthreads();
    if (tid == 0) bsum[blockIdx.x] = ws[0] + ws[1] + ws[2] + ws[3];
}

// phase 2: single small block scans block sums (chunked, carried), writes rowptr[n]=total
__global__ void k_scan_bsum(const int* __restrict__ bsum, int* __restrict__ boff,
                            int* __restrict__ rowptr, int nb, int n) {
    __shared__ int ws[4];
    const int tid = threadIdx.x;
    const int lane = tid & 63;
    const int wave = tid >> 6;
    int carry = 0;
    for (int base = 0; base < nb; base += 256) {
        int i = base + tid;
        int v = (i < nb) ? bsum[i] : 0;
        int incl = v;
#pragma unroll
        for (int off = 1; off < 64; off <<= 1) {
            int t = __shfl_up(incl, off);
            if (lane >= off) incl += t;
        }
        if (lane == 63) ws[wave] = incl;
        __syncthreads();
        int wpre = 0, total = 0;
#pragma unroll
        for (int w = 0; w < 4; ++w) {
            int s = ws[w];
            if (w < wave) wpre += s;
            total += s;
        }
        if (i < nb) boff[i] = carry + wpre + incl - v;
        carry += total;
        __syncthreads();
    }
    if (tid == 0) rowptr[n] = carry;
}

// phase 3: intra-block exclusive scan + block offset; write rowptr/col-selfloop/cursor
__global__ void k_scan_final(const int* __restrict__ hist, const int* __restrict__ boff,
                             int* __restrict__ rowptr, int* __restrict__ cursor,
                             int* __restrict__ col, int n) {
    const int tid = threadIdx.x;
    const int lane = tid & 63;
    const int wave = tid >> 6;
    int idx = blockIdx.x * 256 + tid;
    int v = (idx < n) ? hist[idx] : 0;
    int incl = v;
#pragma unroll
    for (int off = 1; off < 64; off <<= 1) {
        int t = __shfl_up(incl, off);
        if (lane >= off) incl += t;
    }
    __shared__ int ws[4];
    if (lane == 63) ws[wave] = incl;
    __syncthreads();
    int wpre = 0;
#pragma unroll
    for (int w = 0; w < 4; ++w)
        if (w < wave) wpre += ws[w];
    int excl = boff[blockIdx.x] + wpre + incl - v;
    if (idx < n) {
        rowptr[idx] = excl;
        col[excl] = idx;        // self-loop in slot 0 of each segment
        cursor[idx] = excl + 1;
    }
}

__global__ void k_scatter(const int* __restrict__ src, const int* __restrict__ dst,
                          int* cursor, int* col, int E) {
    int i = blockIdx.x * 256 + threadIdx.x;
    if (i < E) {
        int p = atomicAdd(&cursor[dst[i]], 1);
        col[p] = src[i];
    }
}

// ---------------- W1 pre-split + transpose: Wt[col][k] hi/lo bf16 ----------------

__global__ void k_splitw(const float* __restrict__ W, short* __restrict__ Wth,
                         short* __restrict__ Wtl) {
    int colc = blockIdx.x;       // 0..255 (output col)
    int k = threadIdx.x;         // 0..255
    float v = W[(size_t)k * 256 + colc];
    short h, l;
    split_bf16(v, h, l);
    Wth[(size_t)colc * 256 + k] = h;
    Wtl[(size_t)colc * 256 + k] = l;
}

// ---------------- GEMM1 (split-bf16 MFMA): h1[N,256](fp16) = x @ W1, fused alpha1 dots --------
// 128x256 block tile (x read+split ONCE), 512 threads = 8 waves (wr in {0,1}, wc in {0..3}),
// each wave 64x64 = 4x4 MFMA 16x16x32_bf16 tiles. C = Ah*Bh + Ah*Bl + Al*Bh (fp32 acc).
// B staged by plain copies from pre-split transposed W (k_splitw).
// Epilogue: h1 fp16; per-(row,head) a_src/a_dst dots via 16-lane butterfly, plain store.

__global__ __launch_bounds__(512) void k_gemm1(
        const float* __restrict__ x, const short* __restrict__ Wth,
        const short* __restrict__ Wtl, const float* __restrict__ a_src,
        const float* __restrict__ a_dst, _Float16* __restrict__ h1,
        float* __restrict__ as1, float* __restrict__ ad1, int N) {
    __shared__ short Ah[128 * 40];  // [m][k], stride 40
    __shared__ short Al[128 * 40];
    __shared__ short Bh[256 * 40];  // [n][k], stride 40
    __shared__ short Bl[256 * 40];
    const int tid = threadIdx.x;
    const int lane = tid & 63;
    const int wave = tid >> 6;           // 0..7
    const int wr = wave & 1, wc = wave >> 1;
    const int row0 = blockIdx.x * 128;
    const int m15 = lane & 15, quad = lane >> 4;

    f32x4 acc[4][4] = {};

    const int arow = tid >> 2;           // 0..127
    const int akseg = (tid & 3) * 8;     // 0,8,16,24
    const int bcol = tid & 255;          // 0..255
    const int bkh = (tid >> 8) * 16;     // 0 or 16

    for (int k0 = 0; k0 < 256; k0 += 32) {
        // stage A: 128 rows x 32 k, coalesced float4 x2, split hi/lo
        {
            int row = row0 + arow;
            float vals[8];
            if (row < N) {
                float4 v0 = *(const float4*)(x + (size_t)row * 256 + k0 + akseg);
                float4 v1 = *(const float4*)(x + (size_t)row * 256 + k0 + akseg + 4);
                vals[0] = v0.x; vals[1] = v0.y; vals[2] = v0.z; vals[3] = v0.w;
                vals[4] = v1.x; vals[5] = v1.y; vals[6] = v1.z; vals[7] = v1.w;
            } else {
#pragma unroll
                for (int i = 0; i < 8; ++i) vals[i] = 0.f;
            }
            short hbuf[8], lbuf[8];
#pragma unroll
            for (int i = 0; i < 8; ++i) split_bf16(vals[i], hbuf[i], lbuf[i]);
            *(bf16x8*)&Ah[arow * 40 + akseg] = *(bf16x8*)&hbuf[0];
            *(bf16x8*)&Al[arow * 40 + akseg] = *(bf16x8*)&lbuf[0];
        }
        // stage B: plain 16B copies from pre-split transposed W
        {
            *(bf16x8*)&Bh[bcol * 40 + bkh] =
                *(const bf16x8*)(Wth + (size_t)bcol * 256 + k0 + bkh);
            *(bf16x8*)&Bh[bcol * 40 + bkh + 8] =
                *(const bf16x8*)(Wth + (size_t)bcol * 256 + k0 + bkh + 8);
            *(bf16x8*)&Bl[bcol * 40 + bkh] =
                *(const bf16x8*)(Wtl + (size_t)bcol * 256 + k0 + bkh);
            *(bf16x8*)&Bl[bcol * 40 + bkh + 8] =
                *(const bf16x8*)(Wtl + (size_t)bcol * 256 + k0 + bkh + 8);
        }
        __syncthreads();
        bf16x8 ah[4], al[4];
#pragma unroll
        for (int mt = 0; mt < 4; ++mt) {
            int m = wr * 64 + mt * 16 + m15;
            ah[mt] = *(const bf16x8*)&Ah[m * 40 + quad * 8];
            al[mt] = *(const bf16x8*)&Al[m * 40 + quad * 8];
        }
#pragma unroll
        for (int nt = 0; nt < 4; ++nt) {
            int nn = wc * 64 + nt * 16 + m15;
            bf16x8 bh = *(const bf16x8*)&Bh[nn * 40 + quad * 8];
            bf16x8 bl = *(const bf16x8*)&Bl[nn * 40 + quad * 8];
#pragma unroll
            for (int mt = 0; mt < 4; ++mt) {
                acc[mt][nt] = __builtin_amdgcn_mfma_f32_16x16x32_bf16(ah[mt], bh, acc[mt][nt], 0, 0, 0);
                acc[mt][nt] = __builtin_amdgcn_mfma_f32_16x16x32_bf16(ah[mt], bl, acc[mt][nt], 0, 0, 0);
                acc[mt][nt] = __builtin_amdgcn_mfma_f32_16x16x32_bf16(al[mt], bh, acc[mt][nt], 0, 0, 0);
            }
        }
        __syncthreads();
    }
    // epilogue: C/D layout col=lane&15, row=quad*4+reg; wave's 64 cols == head wc
    const int head = wc;
#pragma unroll
    for (int mt = 0; mt < 4; ++mt) {
        float va[4] = {0.f, 0.f, 0.f, 0.f};
        float vd[4] = {0.f, 0.f, 0.f, 0.f};
#pragma unroll
        for (int nt = 0; nt < 4; ++nt) {
            int colg = wc * 64 + nt * 16 + m15;
            float asv = a_src[colg];
            float adv = a_dst[colg];
#pragma unroll
            for (int r = 0; r < 4; ++r) {
                float accv = acc[mt][nt][r];
                int row = row0 + wr * 64 + mt * 16 + quad * 4 + r;
                if (row < N) h1[(size_t)row * 256 + colg] = (_Float16)accv;
                va[r] = fmaf(accv, asv, va[r]);
                vd[r] = fmaf(accv, adv, vd[r]);
            }
        }
#pragma unroll
        for (int r = 0; r < 4; ++r) {
#pragma unroll
            for (int mq = 1; mq < 16; mq <<= 1) {
                va[r] += __shfl_xor(va[r], mq);
                vd[r] += __shfl_xor(vd[r], mq);
            }
            int row = row0 + wr * 64 + mt * 16 + quad * 4 + r;
            if (m15 == 0 && row < N) {
                as1[(size_t)row * 4 + head] = va[r];
                ad1[(size_t)row * 4 + head] = vd[r];
            }
        }
    }
}

// ---------------- gather1 (fused softmax): p computed inline, no alpha/inv arrays -------------
// One wave per dst node; lane covers 4 channels of one head. Unroll 4.
// Denominator s accumulated in-register (identical across lanes of a head group).

__global__ __launch_bounds__(256) void k_gather1(
        const _Float16* __restrict__ h1, const float* __restrict__ as1,
        const float* __restrict__ ad1, const int* __restrict__ rowptr,
        const int* __restrict__ col, const float* __restrict__ b1,
        float* __restrict__ h2in, int N) {
    int n = blockIdx.x * 4 + (threadIdx.x >> 6);
    if (n >= N) return;
    int l = threadIdx.x & 63;
    int head = l >> 4;
    int beg = __builtin_amdgcn_readfirstlane(rowptr[n]);
    int end = __builtin_amdgcn_readfirstlane(rowptr[n + 1]);
    float adv = ad1[(size_t)n * 4 + head];
    float4 a0 = make_float4(0.f, 0.f, 0.f, 0.f);
    float4 a1 = make_float4(0.f, 0.f, 0.f, 0.f);
    float4 a2 = make_float4(0.f, 0.f, 0.f, 0.f);
    float4 a3 = make_float4(0.f, 0.f, 0.f, 0.f);
    float s0 = 0.f, s1 = 0.f, s2 = 0.f, s3 = 0.f;
    int j = beg;
    for (; j + 3 < end; j += 4) {
        int c0 = __builtin_amdgcn_readfirstlane(col[j]);
        int c1 = __builtin_amdgcn_readfirstlane(col[j + 1]);
        int c2 = __builtin_amdgcn_readfirstlane(col[j + 2]);
        int c3 = __builtin_amdgcn_readfirstlane(col[j + 3]);
        float e0 = as1[(size_t)c0 * 4 + head] + adv;
        float e1 = as1[(size_t)c1 * 4 + head] + adv;
        float e2 = as1[(size_t)c2 * 4 + head] + adv;
        float e3 = as1[(size_t)c3 * 4 + head] + adv;
        e0 = fmaxf(e0, NEG_SLOPE * e0); e1 = fmaxf(e1, NEG_SLOPE * e1);
        e2 = fmaxf(e2, NEG_SLOPE * e2); e3 = fmaxf(e3, NEG_SLOPE * e3);
        float p0 = __expf(e0), p1 = __expf(e1), p2 = __expf(e2), p3 = __expf(e3);
        half4v h0 = *((const half4v*)(h1 + (size_t)c0 * 256) + l);
        half4v h1v = *((const half4v*)(h1 + (size_t)c1 * 256) + l);
        half4v h2 = *((const half4v*)(h1 + (size_t)c2 * 256) + l);
        half4v h3 = *((const half4v*)(h1 + (size_t)c3 * 256) + l);
        s0 += p0; s1 += p1; s2 += p2; s3 += p3;
        a0.x = fmaf(p0, (float)h0.x, a0.x); a0.y = fmaf(p0, (float)h0.y, a0.y);
        a0.z = fmaf(p0, (float)h0.z, a0.z); a0.w = fmaf(p0, (float)h0.w, a0.w);
        a1.x = fmaf(p1, (float)h1v.x, a1.x); a1.y = fmaf(p1, (float)h1v.y, a1.y);
        a1.z = fmaf(p1, (float)h1v.z, a1.z); a1.w = fmaf(p1, (float)h1v.w, a1.w);
        a2.x = fmaf(p2, (float)h2.x, a2.x); a2.y = fmaf(p2, (float)h2.y, a2.y);
        a2.z = fmaf(p2, (float)h2.z, a2.z); a2.w = fmaf(p2, (float)h2.w, a2.w);
        a3.x = fmaf(p3, (float)h3.x, a3.x); a3.y = fmaf(p3, (float)h3.y, a3.y);
        a3.z = fmaf(p3, (float)h3.z, a3.z); a3.w = fmaf(p3, (float)h3.w, a3.w);
    }
    for (; j < end; ++j) {
        int c0 = __builtin_amdgcn_readfirstlane(col[j]);
        float e0 = as1[(size_t)c0 * 4 + head] + adv;
        e0 = fmaxf(e0, NEG_SLOPE * e0);
        float p0 = __expf(e0);
        half4v h0 = *((const half4v*)(h1 + (size_t)c0 * 256) + l);
        s0 += p0;
        a0.x = fmaf(p0, (float)h0.x, a0.x); a0.y = fmaf(p0, (float)h0.y, a0.y);
        a0.z = fmaf(p0, (float)h0.z, a0.z); a0.w = fmaf(p0, (float)h0.w, a0.w);
    }
    a0.x += a1.x + a2.x + a3.x;
    a0.y += a1.y + a2.y + a3.y;
    a0.z += a1.z + a2.z + a3.z;
    a0.w += a1.w + a2.w + a3.w;
    float iv = 1.f / ((s0 + s1) + (s2 + s3) + 1e-16f);
    float4 bb = *(const float4*)(b1 + l * 4);
    float4 v;
    v.x = a0.x * iv + bb.x;
    v.y = a0.y * iv + bb.y;
    v.z = a0.z * iv + bb.z;
    v.w = a0.w * iv + bb.w;
    v.x = (v.x > 0.f) ? v.x : (__expf(v.x) - 1.f);
    v.y = (v.y > 0.f) ? v.y : (__expf(v.y) - 1.f);
    v.z = (v.z > 0.f) ? v.z : (__expf(v.z) - 1.f);
    v.w = (v.w > 0.f) ? v.w : (__expf(v.w) - 1.f);
    *(float4*)(h2in + (size_t)n * 256 + l * 4) = v;
}

// ---------------- GEMM2: z[N,32] = h2in[N,256] @ W2[256,32], fused alpha2 dots ----------------

__global__ __launch_bounds__(256) void k_gemm2(const float* __restrict__ h,
                                               const float* __restrict__ W2,
                                               const float* __restrict__ asrc,
                                               const float* __restrict__ adst,
                                               float* __restrict__ z, float* __restrict__ as2,
                                               float* __restrict__ ad2, int N) {
    __shared__ float Ws[256 * 32];
    __shared__ float Hs[32 * 68];
    const int tid = threadIdx.x;
    const int r = tid >> 3;
    const int cg = tid & 7;
    const int row0 = blockIdx.x * 32;
    const int row = row0 + r;
    for (int i = tid; i < 256 * 32; i += 256) Ws[i] = W2[i];
    float4 acc = make_float4(0.f, 0.f, 0.f, 0.f);
    for (int k0 = 0; k0 < 256; k0 += 64) {
        __syncthreads();
#pragma unroll
        for (int i = 0; i < 2; ++i) {
            int idx = tid + 256 * i;
            int rr = idx >> 4;
            int c4 = (idx & 15) * 4;
            int rw = row0 + rr;
            float4 v = (rw < N) ? *(const float4*)(h + (size_t)rw * 256 + k0 + c4)
                                : make_float4(0.f, 0.f, 0.f, 0.f);
            *(float4*)(Hs + rr * 68 + c4) = v;
        }
        __syncthreads();
#pragma unroll
        for (int k = 0; k < 64; k += 4) {
            float4 hv = *(const float4*)(Hs + r * 68 + k);
            float4 w0 = *(const float4*)(Ws + (k0 + k) * 32 + cg * 4);
            float4 w1 = *(const float4*)(Ws + (k0 + k + 1) * 32 + cg * 4);
            float4 w2 = *(const float4*)(Ws + (k0 + k + 2) * 32 + cg * 4);
            float4 w3 = *(const float4*)(Ws + (k0 + k + 3) * 32 + cg * 4);
            acc.x = fmaf(hv.x, w0.x, acc.x); acc.y = fmaf(hv.x, w0.y, acc.y);
            acc.z = fmaf(hv.x, w0.z, acc.z); acc.w = fmaf(hv.x, w0.w, acc.w);
            acc.x = fmaf(hv.y, w1.x, acc.x); acc.y = fmaf(hv.y, w1.y, acc.y);
            acc.z = fmaf(hv.y, w1.z, acc.z); acc.w = fmaf(hv.y, w1.w, acc.w);
            acc.x = fmaf(hv.z, w2.x, acc.x); acc.y = fmaf(hv.z, w2.y, acc.y);
            acc.z = fmaf(hv.z, w2.z, acc.z); acc.w = fmaf(hv.z, w2.w, acc.w);
            acc.x = fmaf(hv.w, w3.x, acc.x); acc.y = fmaf(hv.w, w3.y, acc.y);
            acc.z = fmaf(hv.w, w3.z, acc.z); acc.w = fmaf(hv.w, w3.w, acc.w);
        }
    }
    float4 a4 = *(const float4*)(asrc + cg * 4);
    float4 d4 = *(const float4*)(adst + cg * 4);
    float va = acc.x * a4.x + acc.y * a4.y + acc.z * a4.z + acc.w * a4.w;
    float vd = acc.x * d4.x + acc.y * d4.y + acc.z * d4.z + acc.w * d4.w;
#pragma unroll
    for (int mq = 1; mq < 8; mq <<= 1) {
        va += __shfl_xor(va, mq);
        vd += __shfl_xor(vd, mq);
    }
    if (row < N) {
        *(float4*)(z + (size_t)row * 32 + cg * 4) = acc;
        if (cg == 0) {
            as2[row] = va;
            ad2[row] = vd;
        }
    }
}

// ---------------- gather2 (fused softmax): out = (sum_j p_j * z[src_j]) / sum_j p_j + b2 ------
// One wave per node; 8 edges in parallel (eo=lane>>3), 8 channel-groups (cg=lane&7, x4 ch).

__global__ void k_gather2(const float* __restrict__ z, const float* __restrict__ as2,
                          const float* __restrict__ ad2, const int* __restrict__ rowptr,
                          const int* __restrict__ col, const float* __restrict__ b2,
                          float* __restrict__ out, int N) {
    int n = blockIdx.x * 4 + (threadIdx.x >> 6);
    if (n >= N) return;
    int l = threadIdx.x & 63;
    int eo = l >> 3;
    int cg = l & 7;
    int beg = __builtin_amdgcn_readfirstlane(rowptr[n]);
    int end = __builtin_amdgcn_readfirstlane(rowptr[n + 1]);
    float adn = ad2[n];
    float4 acc = make_float4(0.f, 0.f, 0.f, 0.f);
    float s = 0.f;
    for (int j0 = beg; j0 < end; j0 += 8) {
        int idx = j0 + eo;
        bool valid = idx < end;
        int idc = valid ? idx : (end - 1);
        int src = col[idc];
        float e = as2[src] + adn;
        e = fmaxf(e, NEG_SLOPE * e);
        float p = valid ? __expf(e) : 0.f;
        float4 zv = *(const float4*)(z + (size_t)src * 32 + cg * 4);
        s += p;
        acc.x = fmaf(p, zv.x, acc.x); acc.y = fmaf(p, zv.y, acc.y);
        acc.z = fmaf(p, zv.z, acc.z); acc.w = fmaf(p, zv.w, acc.w);
    }
#pragma unroll
    for (int mq = 8; mq < 64; mq <<= 1) {
        acc.x += __shfl_xor(acc.x, mq);
        acc.y += __shfl_xor(acc.y, mq);
        acc.z += __shfl_xor(acc.z, mq);
        acc.w += __shfl_xor(acc.w, mq);
        s += __shfl_xor(s, mq);
    }
    if (eo == 0) {
        float iv = 1.f / (s + 1e-16f);
        float4 bb = *(const float4*)(b2 + cg * 4);
        float4 v;
        v.x = acc.x * iv + bb.x;
        v.y = acc.y * iv + bb.y;
        v.z = acc.z * iv + bb.z;
        v.w = acc.w * iv + bb.w;
        *(float4*)(out + (size_t)n * 32 + cg * 4) = v;
    }
}

// ---------------- launch ----------------

extern "C" void kernel_launch(void* const* d_in, const int* in_sizes, int n_in,
                              void* d_out, int out_size, void* d_ws, size_t ws_size,
                              hipStream_t stream) {
    const float* x    = (const float*)d_in[0];
    const int*   ei   = (const int*)d_in[1];
    const float* W1   = (const float*)d_in[2];
    const float* a_s1 = (const float*)d_in[3];
    const float* a_d1 = (const float*)d_in[4];
    const float* b1   = (const float*)d_in[5];
    const float* W2   = (const float*)d_in[6];
    const float* a_s2 = (const float*)d_in[7];
    const float* a_d2 = (const float*)d_in[8];
    const float* b2   = (const float*)d_in[9];
    float* out = (float*)d_out;

    const int N = in_sizes[0] / 256;
    const int E = in_sizes[1] / 2;
    const int EP = E + N;  // with self-loops
    const int* srcIdx = ei;
    const int* dstIdx = ei + E;
    const int NB = (N + 255) / 256;

    char* ws = (char*)d_ws;
    size_t off = 0;
    auto alloc = [&](size_t bytes) {
        void* p = ws + off;
        off += (bytes + 255) & ~(size_t)255;
        return p;
    };
    _Float16* h1  = (_Float16*)alloc((size_t)N * 256 * 2);  // fp16 gather table
    float* h2in   = (float*)alloc((size_t)N * 256 * 4);
    float* z      = (float*)alloc((size_t)N * 32 * 4);
    float* as1    = (float*)alloc((size_t)N * 16);          // reused as as2
    float* ad1    = (float*)alloc((size_t)N * 16);          // reused as ad2
    short* Wth    = (short*)alloc((size_t)256 * 256 * 2);
    short* Wtl    = (short*)alloc((size_t)256 * 256 * 2);
    int*   hist   = (int*)alloc((size_t)N * 4);
    int*   cursor = (int*)alloc((size_t)N * 4);
    int*   rowptr = (int*)alloc((size_t)(N + 1) * 4);
    int*   col    = (int*)alloc((size_t)EP * 4);
    int*   bsum   = (int*)alloc((size_t)NB * 4);
    int*   boff   = (int*)alloc((size_t)NB * 4);

    float* as2 = as1;
    float* ad2 = ad1;

    // CSR build (dst-sorted adjacency, self-loops included), parallel 3-phase scan
    k_init<<<NB, 256, 0, stream>>>(hist, N);
    k_count<<<(E + 255) / 256, 256, 0, stream>>>(dstIdx, hist, E);
    k_splitw<<<256, 256, 0, stream>>>(W1, Wth, Wtl);  // independent of CSR
    k_bsum<<<NB, 256, 0, stream>>>(hist, bsum, N);
    k_scan_bsum<<<1, 256, 0, stream>>>(bsum, boff, rowptr, NB, N);
    k_scan_final<<<NB, 256, 0, stream>>>(hist, boff, rowptr, cursor, col, N);
    k_scatter<<<(E + 255) / 256, 256, 0, stream>>>(srcIdx, dstIdx, cursor, col, E);

    // layer 1
    k_gemm1<<<(N + 127) / 128, 512, 0, stream>>>(x, Wth, Wtl, a_s1, a_d1, h1, as1, ad1, N);
    k_gather1<<<(N + 3) / 4, 256, 0, stream>>>(h1, as1, ad1, rowptr, col, b1, h2in, N);

    // layer 2
    k_gemm2<<<(N + 31) / 32, 256, 0, stream>>>(h2in, W2, a_s2, a_d2, z, as2, ad2, N);
    k_gather2<<<(N + 3) / 4, 256, 0, stream>>>(z, as2, ad2, rowptr, col, b2, out, N);
}

// Round 7
// 330.091 us; speedup vs baseline: 1.6973x; 1.0675x over previous
//
#include <hip/hip_runtime.h>

#define NEG_SLOPE 0.2f

typedef short bf16x8 __attribute__((ext_vector_type(8)));
typedef float f32x4 __attribute__((ext_vector_type(4)));
typedef _Float16 half4v __attribute__((ext_vector_type(4)));
typedef _Float16 half8v __attribute__((ext_vector_type(8)));

// split fp32 into hi (truncated bf16) + lo (RNE bf16 of remainder): x ~= hi + lo, err ~2^-17*x
__device__ inline void split_bf16(float x, short& hi, short& lo) {
    unsigned xb = __float_as_uint(x);
    hi = (short)(xb >> 16);
    float hif = __uint_as_float(xb & 0xFFFF0000u);
    float rem = x - hif;
    unsigned rb = __float_as_uint(rem);
    unsigned r = rb + 0x7FFFu + ((rb >> 16) & 1u);
    lo = (short)(r >> 16);
}

// ---------------- CSR build ----------------

__global__ void k_init(int* hist, int N) {
    int i = blockIdx.x * 256 + threadIdx.x;
    if (i < N) hist[i] = 1;  // self-loop pre-counted
}

__global__ void k_count(const int* __restrict__ dst, int* hist, int E) {
    int i = blockIdx.x * 256 + threadIdx.x;
    if (i < E) atomicAdd(&hist[dst[i]], 1);
}

// phase 1: per-block (256-elt) sums of hist
__global__ void k_bsum(const int* __restrict__ hist, int* __restrict__ bsum, int n) {
    const int tid = threadIdx.x;
    const int lane = tid & 63;
    const int wave = tid >> 6;
    int idx = blockIdx.x * 256 + tid;
    int v = (idx < n) ? hist[idx] : 0;
#pragma unroll
    for (int mq = 1; mq < 64; mq <<= 1) v += __shfl_xor(v, mq);
    __shared__ int ws[4];
    if (lane == 0) ws[wave] = v;
    __syncthreads();
    if (tid == 0) bsum[blockIdx.x] = ws[0] + ws[1] + ws[2] + ws[3];
}

// phase 2: single small block scans block sums (chunked, carried), writes rowptr[n]=total
__global__ void k_scan_bsum(const int* __restrict__ bsum, int* __restrict__ boff,
                            int* __restrict__ rowptr, int nb, int n) {
    __shared__ int ws[4];
    const int tid = threadIdx.x;
    const int lane = tid & 63;
    const int wave = tid >> 6;
    int carry = 0;
    for (int base = 0; base < nb; base += 256) {
        int i = base + tid;
        int v = (i < nb) ? bsum[i] : 0;
        int incl = v;
#pragma unroll
        for (int off = 1; off < 64; off <<= 1) {
            int t = __shfl_up(incl, off);
            if (lane >= off) incl += t;
        }
        if (lane == 63) ws[wave] = incl;
        __syncthreads();
        int wpre = 0, total = 0;
#pragma unroll
        for (int w = 0; w < 4; ++w) {
            int s = ws[w];
            if (w < wave) wpre += s;
            total += s;
        }
        if (i < nb) boff[i] = carry + wpre + incl - v;
        carry += total;
        __syncthreads();
    }
    if (tid == 0) rowptr[n] = carry;
}

// phase 3: intra-block exclusive scan + block offset; write rowptr/col-selfloop/cursor
__global__ void k_scan_final(const int* __restrict__ hist, const int* __restrict__ boff,
                             int* __restrict__ rowptr, int* __restrict__ cursor,
                             int* __restrict__ col, int n) {
    const int tid = threadIdx.x;
    const int lane = tid & 63;
    const int wave = tid >> 6;
    int idx = blockIdx.x * 256 + tid;
    int v = (idx < n) ? hist[idx] : 0;
    int incl = v;
#pragma unroll
    for (int off = 1; off < 64; off <<= 1) {
        int t = __shfl_up(incl, off);
        if (lane >= off) incl += t;
    }
    __shared__ int ws[4];
    if (lane == 63) ws[wave] = incl;
    __syncthreads();
    int wpre = 0;
#pragma unroll
    for (int w = 0; w < 4; ++w)
        if (w < wave) wpre += ws[w];
    int excl = boff[blockIdx.x] + wpre + incl - v;
    if (idx < n) {
        rowptr[idx] = excl;
        col[excl] = idx;        // self-loop in slot 0 of each segment
        cursor[idx] = excl + 1;
    }
}

__global__ void k_scatter(const int* __restrict__ src, const int* __restrict__ dst,
                          int* cursor, int* col, int E) {
    int i = blockIdx.x * 256 + threadIdx.x;
    if (i < E) {
        int p = atomicAdd(&cursor[dst[i]], 1);
        col[p] = src[i];
    }
}

// ---------------- W1 pre-split + transpose: Wt[col][k] hi/lo bf16 ----------------

__global__ void k_splitw(const float* __restrict__ W, short* __restrict__ Wth,
                         short* __restrict__ Wtl) {
    int colc = blockIdx.x;       // 0..255 (output col)
    int k = threadIdx.x;         // 0..255
    float v = W[(size_t)k * 256 + colc];
    short h, l;
    split_bf16(v, h, l);
    Wth[(size_t)colc * 256 + k] = h;
    Wtl[(size_t)colc * 256 + k] = l;
}

// ---------------- GEMM1 (split-bf16 MFMA): h1[N,256](fp16) = x @ W1, fused alpha1 dots --------
// 128x256 block tile (x read+split ONCE), 512 threads = 8 waves (wr in {0,1}, wc in {0..3}),
// each wave 64x64 = 4x4 MFMA 16x16x32_bf16 tiles. C = Ah*Bh + Ah*Bl + Al*Bh (fp32 acc).

__global__ __launch_bounds__(512) void k_gemm1(
        const float* __restrict__ x, const short* __restrict__ Wth,
        const short* __restrict__ Wtl, const float* __restrict__ a_src,
        const float* __restrict__ a_dst, _Float16* __restrict__ h1,
        float* __restrict__ as1, float* __restrict__ ad1, int N) {
    __shared__ short Ah[128 * 40];  // [m][k], stride 40
    __shared__ short Al[128 * 40];
    __shared__ short Bh[256 * 40];  // [n][k], stride 40
    __shared__ short Bl[256 * 40];
    const int tid = threadIdx.x;
    const int lane = tid & 63;
    const int wave = tid >> 6;           // 0..7
    const int wr = wave & 1, wc = wave >> 1;
    const int row0 = blockIdx.x * 128;
    const int m15 = lane & 15, quad = lane >> 4;

    f32x4 acc[4][4] = {};

    const int arow = tid >> 2;           // 0..127
    const int akseg = (tid & 3) * 8;     // 0,8,16,24
    const int bcol = tid & 255;          // 0..255
    const int bkh = (tid >> 8) * 16;     // 0 or 16

    for (int k0 = 0; k0 < 256; k0 += 32) {
        {
            int row = row0 + arow;
            float vals[8];
            if (row < N) {
                float4 v0 = *(const float4*)(x + (size_t)row * 256 + k0 + akseg);
                float4 v1 = *(const float4*)(x + (size_t)row * 256 + k0 + akseg + 4);
                vals[0] = v0.x; vals[1] = v0.y; vals[2] = v0.z; vals[3] = v0.w;
                vals[4] = v1.x; vals[5] = v1.y; vals[6] = v1.z; vals[7] = v1.w;
            } else {
#pragma unroll
                for (int i = 0; i < 8; ++i) vals[i] = 0.f;
            }
            short hbuf[8], lbuf[8];
#pragma unroll
            for (int i = 0; i < 8; ++i) split_bf16(vals[i], hbuf[i], lbuf[i]);
            *(bf16x8*)&Ah[arow * 40 + akseg] = *(bf16x8*)&hbuf[0];
            *(bf16x8*)&Al[arow * 40 + akseg] = *(bf16x8*)&lbuf[0];
        }
        {
            *(bf16x8*)&Bh[bcol * 40 + bkh] =
                *(const bf16x8*)(Wth + (size_t)bcol * 256 + k0 + bkh);
            *(bf16x8*)&Bh[bcol * 40 + bkh + 8] =
                *(const bf16x8*)(Wth + (size_t)bcol * 256 + k0 + bkh + 8);
            *(bf16x8*)&Bl[bcol * 40 + bkh] =
                *(const bf16x8*)(Wtl + (size_t)bcol * 256 + k0 + bkh);
            *(bf16x8*)&Bl[bcol * 40 + bkh + 8] =
                *(const bf16x8*)(Wtl + (size_t)bcol * 256 + k0 + bkh + 8);
        }
        __syncthreads();
        bf16x8 ah[4], al[4];
#pragma unroll
        for (int mt = 0; mt < 4; ++mt) {
            int m = wr * 64 + mt * 16 + m15;
            ah[mt] = *(const bf16x8*)&Ah[m * 40 + quad * 8];
            al[mt] = *(const bf16x8*)&Al[m * 40 + quad * 8];
        }
#pragma unroll
        for (int nt = 0; nt < 4; ++nt) {
            int nn = wc * 64 + nt * 16 + m15;
            bf16x8 bh = *(const bf16x8*)&Bh[nn * 40 + quad * 8];
            bf16x8 bl = *(const bf16x8*)&Bl[nn * 40 + quad * 8];
#pragma unroll
            for (int mt = 0; mt < 4; ++mt) {
                acc[mt][nt] = __builtin_amdgcn_mfma_f32_16x16x32_bf16(ah[mt], bh, acc[mt][nt], 0, 0, 0);
                acc[mt][nt] = __builtin_amdgcn_mfma_f32_16x16x32_bf16(ah[mt], bl, acc[mt][nt], 0, 0, 0);
                acc[mt][nt] = __builtin_amdgcn_mfma_f32_16x16x32_bf16(al[mt], bh, acc[mt][nt], 0, 0, 0);
            }
        }
        __syncthreads();
    }
    // epilogue: C/D layout col=lane&15, row=quad*4+reg; wave's 64 cols == head wc
    const int head = wc;
#pragma unroll
    for (int mt = 0; mt < 4; ++mt) {
        float va[4] = {0.f, 0.f, 0.f, 0.f};
        float vd[4] = {0.f, 0.f, 0.f, 0.f};
#pragma unroll
        for (int nt = 0; nt < 4; ++nt) {
            int colg = wc * 64 + nt * 16 + m15;
            float asv = a_src[colg];
            float adv = a_dst[colg];
#pragma unroll
            for (int r = 0; r < 4; ++r) {
                float accv = acc[mt][nt][r];
                int row = row0 + wr * 64 + mt * 16 + quad * 4 + r;
                if (row < N) h1[(size_t)row * 256 + colg] = (_Float16)accv;
                va[r] = fmaf(accv, asv, va[r]);
                vd[r] = fmaf(accv, adv, vd[r]);
            }
        }
#pragma unroll
        for (int r = 0; r < 4; ++r) {
#pragma unroll
            for (int mq = 1; mq < 16; mq <<= 1) {
                va[r] += __shfl_xor(va[r], mq);
                vd[r] += __shfl_xor(vd[r], mq);
            }
            int row = row0 + wr * 64 + mt * 16 + quad * 4 + r;
            if (m15 == 0 && row < N) {
                as1[(size_t)row * 4 + head] = va[r];
                ad1[(size_t)row * 4 + head] = vd[r];
            }
        }
    }
}

// ---------------- gather1 (fused softmax): h2in (fp16) = softmax-aggregate + bias + ELU -------

__global__ __launch_bounds__(256) void k_gather1(
        const _Float16* __restrict__ h1, const float* __restrict__ as1,
        const float* __restrict__ ad1, const int* __restrict__ rowptr,
        const int* __restrict__ col, const float* __restrict__ b1,
        _Float16* __restrict__ h2in, int N) {
    int n = blockIdx.x * 4 + (threadIdx.x >> 6);
    if (n >= N) return;
    int l = threadIdx.x & 63;
    int head = l >> 4;
    int beg = __builtin_amdgcn_readfirstlane(rowptr[n]);
    int end = __builtin_amdgcn_readfirstlane(rowptr[n + 1]);
    float adv = ad1[(size_t)n * 4 + head];
    float4 a0 = make_float4(0.f, 0.f, 0.f, 0.f);
    float4 a1 = make_float4(0.f, 0.f, 0.f, 0.f);
    float4 a2 = make_float4(0.f, 0.f, 0.f, 0.f);
    float4 a3 = make_float4(0.f, 0.f, 0.f, 0.f);
    float s0 = 0.f, s1 = 0.f, s2 = 0.f, s3 = 0.f;
    int j = beg;
    for (; j + 3 < end; j += 4) {
        int c0 = __builtin_amdgcn_readfirstlane(col[j]);
        int c1 = __builtin_amdgcn_readfirstlane(col[j + 1]);
        int c2 = __builtin_amdgcn_readfirstlane(col[j + 2]);
        int c3 = __builtin_amdgcn_readfirstlane(col[j + 3]);
        float e0 = as1[(size_t)c0 * 4 + head] + adv;
        float e1 = as1[(size_t)c1 * 4 + head] + adv;
        float e2 = as1[(size_t)c2 * 4 + head] + adv;
        float e3 = as1[(size_t)c3 * 4 + head] + adv;
        e0 = fmaxf(e0, NEG_SLOPE * e0); e1 = fmaxf(e1, NEG_SLOPE * e1);
        e2 = fmaxf(e2, NEG_SLOPE * e2); e3 = fmaxf(e3, NEG_SLOPE * e3);
        float p0 = __expf(e0), p1 = __expf(e1), p2 = __expf(e2), p3 = __expf(e3);
        half4v h0 = *((const half4v*)(h1 + (size_t)c0 * 256) + l);
        half4v h1v = *((const half4v*)(h1 + (size_t)c1 * 256) + l);
        half4v h2 = *((const half4v*)(h1 + (size_t)c2 * 256) + l);
        half4v h3 = *((const half4v*)(h1 + (size_t)c3 * 256) + l);
        s0 += p0; s1 += p1; s2 += p2; s3 += p3;
        a0.x = fmaf(p0, (float)h0.x, a0.x); a0.y = fmaf(p0, (float)h0.y, a0.y);
        a0.z = fmaf(p0, (float)h0.z, a0.z); a0.w = fmaf(p0, (float)h0.w, a0.w);
        a1.x = fmaf(p1, (float)h1v.x, a1.x); a1.y = fmaf(p1, (float)h1v.y, a1.y);
        a1.z = fmaf(p1, (float)h1v.z, a1.z); a1.w = fmaf(p1, (float)h1v.w, a1.w);
        a2.x = fmaf(p2, (float)h2.x, a2.x); a2.y = fmaf(p2, (float)h2.y, a2.y);
        a2.z = fmaf(p2, (float)h2.z, a2.z); a2.w = fmaf(p2, (float)h2.w, a2.w);
        a3.x = fmaf(p3, (float)h3.x, a3.x); a3.y = fmaf(p3, (float)h3.y, a3.y);
        a3.z = fmaf(p3, (float)h3.z, a3.z); a3.w = fmaf(p3, (float)h3.w, a3.w);
    }
    for (; j < end; ++j) {
        int c0 = __builtin_amdgcn_readfirstlane(col[j]);
        float e0 = as1[(size_t)c0 * 4 + head] + adv;
        e0 = fmaxf(e0, NEG_SLOPE * e0);
        float p0 = __expf(e0);
        half4v h0 = *((const half4v*)(h1 + (size_t)c0 * 256) + l);
        s0 += p0;
        a0.x = fmaf(p0, (float)h0.x, a0.x); a0.y = fmaf(p0, (float)h0.y, a0.y);
        a0.z = fmaf(p0, (float)h0.z, a0.z); a0.w = fmaf(p0, (float)h0.w, a0.w);
    }
    a0.x += a1.x + a2.x + a3.x;
    a0.y += a1.y + a2.y + a3.y;
    a0.z += a1.z + a2.z + a3.z;
    a0.w += a1.w + a2.w + a3.w;
    float iv = 1.f / ((s0 + s1) + (s2 + s3) + 1e-16f);
    float4 bb = *(const float4*)(b1 + l * 4);
    float4 v;
    v.x = a0.x * iv + bb.x;
    v.y = a0.y * iv + bb.y;
    v.z = a0.z * iv + bb.z;
    v.w = a0.w * iv + bb.w;
    v.x = (v.x > 0.f) ? v.x : (__expf(v.x) - 1.f);
    v.y = (v.y > 0.f) ? v.y : (__expf(v.y) - 1.f);
    v.z = (v.z > 0.f) ? v.z : (__expf(v.z) - 1.f);
    v.w = (v.w > 0.f) ? v.w : (__expf(v.w) - 1.f);
    half4v hv;
    hv.x = (_Float16)v.x; hv.y = (_Float16)v.y; hv.z = (_Float16)v.z; hv.w = (_Float16)v.w;
    *((half4v*)(h2in + (size_t)n * 256) + l) = hv;
}

// ---------------- GEMM2: z[N,32](fp16) = h2in[N,256](fp16) @ W2[256,32], fused alpha2 dots ----

__global__ __launch_bounds__(256) void k_gemm2(const _Float16* __restrict__ h,
                                               const float* __restrict__ W2,
                                               const float* __restrict__ asrc,
                                               const float* __restrict__ adst,
                                               _Float16* __restrict__ z, float* __restrict__ as2,
                                               float* __restrict__ ad2, int N) {
    __shared__ float Ws[256 * 32];
    __shared__ float Hs[32 * 68];
    const int tid = threadIdx.x;
    const int r = tid >> 3;
    const int cg = tid & 7;
    const int row0 = blockIdx.x * 32;
    const int row = row0 + r;
    for (int i = tid; i < 256 * 32; i += 256) Ws[i] = W2[i];
    float4 acc = make_float4(0.f, 0.f, 0.f, 0.f);
    for (int k0 = 0; k0 < 256; k0 += 64) {
        __syncthreads();
        {
            int rr = tid >> 3;           // 0..31
            int c8 = (tid & 7) * 8;      // 0..56
            int rw = row0 + rr;
            float f[8];
            if (rw < N) {
                half8v v = *(const half8v*)(h + (size_t)rw * 256 + k0 + c8);
#pragma unroll
                for (int i = 0; i < 8; ++i) f[i] = (float)v[i];
            } else {
#pragma unroll
                for (int i = 0; i < 8; ++i) f[i] = 0.f;
            }
#pragma unroll
            for (int i = 0; i < 8; ++i) Hs[rr * 68 + c8 + i] = f[i];
        }
        __syncthreads();
#pragma unroll
        for (int k = 0; k < 64; k += 4) {
            float4 hv = *(const float4*)(Hs + r * 68 + k);
            float4 w0 = *(const float4*)(Ws + (k0 + k) * 32 + cg * 4);
            float4 w1 = *(const float4*)(Ws + (k0 + k + 1) * 32 + cg * 4);
            float4 w2 = *(const float4*)(Ws + (k0 + k + 2) * 32 + cg * 4);
            float4 w3 = *(const float4*)(Ws + (k0 + k + 3) * 32 + cg * 4);
            acc.x = fmaf(hv.x, w0.x, acc.x); acc.y = fmaf(hv.x, w0.y, acc.y);
            acc.z = fmaf(hv.x, w0.z, acc.z); acc.w = fmaf(hv.x, w0.w, acc.w);
            acc.x = fmaf(hv.y, w1.x, acc.x); acc.y = fmaf(hv.y, w1.y, acc.y);
            acc.z = fmaf(hv.y, w1.z, acc.z); acc.w = fmaf(hv.y, w1.w, acc.w);
            acc.x = fmaf(hv.z, w2.x, acc.x); acc.y = fmaf(hv.z, w2.y, acc.y);
            acc.z = fmaf(hv.z, w2.z, acc.z); acc.w = fmaf(hv.z, w2.w, acc.w);
            acc.x = fmaf(hv.w, w3.x, acc.x); acc.y = fmaf(hv.w, w3.y, acc.y);
            acc.z = fmaf(hv.w, w3.z, acc.z); acc.w = fmaf(hv.w, w3.w, acc.w);
        }
    }
    float4 a4 = *(const float4*)(asrc + cg * 4);
    float4 d4 = *(const float4*)(adst + cg * 4);
    float va = acc.x * a4.x + acc.y * a4.y + acc.z * a4.z + acc.w * a4.w;
    float vd = acc.x * d4.x + acc.y * d4.y + acc.z * d4.z + acc.w * d4.w;
#pragma unroll
    for (int mq = 1; mq < 8; mq <<= 1) {
        va += __shfl_xor(va, mq);
        vd += __shfl_xor(vd, mq);
    }
    if (row < N) {
        half4v zv;
        zv.x = (_Float16)acc.x; zv.y = (_Float16)acc.y;
        zv.z = (_Float16)acc.z; zv.w = (_Float16)acc.w;
        *((half4v*)(z + (size_t)row * 32) + cg) = zv;
        if (cg == 0) {
            as2[row] = va;
            ad2[row] = vd;
        }
    }
}

// ---------------- gather2 (fused softmax): out = (sum_j p_j * z[src_j]) / sum_j p_j + b2 ------
// One wave per node; 8 edges in parallel (eo=lane>>3), 8 channel-groups (cg=lane&7, x4 ch fp16).

__global__ void k_gather2(const _Float16* __restrict__ z, const float* __restrict__ as2,
                          const float* __restrict__ ad2, const int* __restrict__ rowptr,
                          const int* __restrict__ col, const float* __restrict__ b2,
                          float* __restrict__ out, int N) {
    int n = blockIdx.x * 4 + (threadIdx.x >> 6);
    if (n >= N) return;
    int l = threadIdx.x & 63;
    int eo = l >> 3;
    int cg = l & 7;
    int beg = __builtin_amdgcn_readfirstlane(rowptr[n]);
    int end = __builtin_amdgcn_readfirstlane(rowptr[n + 1]);
    float adn = ad2[n];
    float4 acc = make_float4(0.f, 0.f, 0.f, 0.f);
    float s = 0.f;
    for (int j0 = beg; j0 < end; j0 += 8) {
        int idx = j0 + eo;
        bool valid = idx < end;
        int idc = valid ? idx : (end - 1);
        int src = col[idc];
        float e = as2[src] + adn;
        e = fmaxf(e, NEG_SLOPE * e);
        float p = valid ? __expf(e) : 0.f;
        half4v zv = *((const half4v*)(z + (size_t)src * 32) + cg);
        s += p;
        acc.x = fmaf(p, (float)zv.x, acc.x); acc.y = fmaf(p, (float)zv.y, acc.y);
        acc.z = fmaf(p, (float)zv.z, acc.z); acc.w = fmaf(p, (float)zv.w, acc.w);
    }
#pragma unroll
    for (int mq = 8; mq < 64; mq <<= 1) {
        acc.x += __shfl_xor(acc.x, mq);
        acc.y += __shfl_xor(acc.y, mq);
        acc.z += __shfl_xor(acc.z, mq);
        acc.w += __shfl_xor(acc.w, mq);
        s += __shfl_xor(s, mq);
    }
    if (eo == 0) {
        float iv = 1.f / (s + 1e-16f);
        float4 bb = *(const float4*)(b2 + cg * 4);
        float4 v;
        v.x = acc.x * iv + bb.x;
        v.y = acc.y * iv + bb.y;
        v.z = acc.z * iv + bb.z;
        v.w = acc.w * iv + bb.w;
        *(float4*)(out + (size_t)n * 32 + cg * 4) = v;
    }
}

// ---------------- launch ----------------

extern "C" void kernel_launch(void* const* d_in, const int* in_sizes, int n_in,
                              void* d_out, int out_size, void* d_ws, size_t ws_size,
                              hipStream_t stream) {
    const float* x    = (const float*)d_in[0];
    const int*   ei   = (const int*)d_in[1];
    const float* W1   = (const float*)d_in[2];
    const float* a_s1 = (const float*)d_in[3];
    const float* a_d1 = (const float*)d_in[4];
    const float* b1   = (const float*)d_in[5];
    const float* W2   = (const float*)d_in[6];
    const float* a_s2 = (const float*)d_in[7];
    const float* a_d2 = (const float*)d_in[8];
    const float* b2   = (const float*)d_in[9];
    float* out = (float*)d_out;

    const int N = in_sizes[0] / 256;
    const int E = in_sizes[1] / 2;
    const int EP = E + N;  // with self-loops
    const int* srcIdx = ei;
    const int* dstIdx = ei + E;
    const int NB = (N + 255) / 256;

    char* ws = (char*)d_ws;
    size_t off = 0;
    auto alloc = [&](size_t bytes) {
        void* p = ws + off;
        off += (bytes + 255) & ~(size_t)255;
        return p;
    };
    _Float16* h1   = (_Float16*)alloc((size_t)N * 256 * 2);  // fp16 gather table (layer1)
    _Float16* h2in = (_Float16*)alloc((size_t)N * 256 * 2);  // fp16 gemm2 input
    _Float16* z    = (_Float16*)alloc((size_t)N * 32 * 2);   // fp16 gather table (layer2)
    float* as1    = (float*)alloc((size_t)N * 16);           // reused as as2
    float* ad1    = (float*)alloc((size_t)N * 16);           // reused as ad2
    short* Wth    = (short*)alloc((size_t)256 * 256 * 2);
    short* Wtl    = (short*)alloc((size_t)256 * 256 * 2);
    int*   hist   = (int*)alloc((size_t)N * 4);
    int*   cursor = (int*)alloc((size_t)N * 4);
    int*   rowptr = (int*)alloc((size_t)(N + 1) * 4);
    int*   col    = (int*)alloc((size_t)EP * 4);
    int*   bsum   = (int*)alloc((size_t)NB * 4);
    int*   boff   = (int*)alloc((size_t)NB * 4);

    float* as2 = as1;
    float* ad2 = ad1;

    // CSR build (dst-sorted adjacency, self-loops included), parallel 3-phase scan
    k_init<<<NB, 256, 0, stream>>>(hist, N);
    k_count<<<(E + 255) / 256, 256, 0, stream>>>(dstIdx, hist, E);
    k_splitw<<<256, 256, 0, stream>>>(W1, Wth, Wtl);  // independent of CSR
    k_bsum<<<NB, 256, 0, stream>>>(hist, bsum, N);
    k_scan_bsum<<<1, 256, 0, stream>>>(bsum, boff, rowptr, NB, N);
    k_scan_final<<<NB, 256, 0, stream>>>(hist, boff, rowptr, cursor, col, N);
    k_scatter<<<(E + 255) / 256, 256, 0, stream>>>(srcIdx, dstIdx, cursor, col, E);

    // layer 1
    k_gemm1<<<(N + 127) / 128, 512, 0, stream>>>(x, Wth, Wtl, a_s1, a_d1, h1, as1, ad1, N);
    k_gather1<<<(N + 3) / 4, 256, 0, stream>>>(h1, as1, ad1, rowptr, col, b1, h2in, N);

    // layer 2
    k_gemm2<<<(N + 31) / 32, 256, 0, stream>>>(h2in, W2, a_s2, a_d2, z, as2, ad2, N);
    k_gather2<<<(N + 3) / 4, 256, 0, stream>>>(z, as2, ad2, rowptr, col, b2, out, N);
}